// Round 8
// baseline (430.685 us; speedup 1.0000x reference)
//
#include <hip/hip_runtime.h>
#include <math.h>

#define B 4
#define L 4096
#define D 1024
#define H 16
#define DK 64
#define M 256
#define NTOK (B*L)        // 16384
#define NCH 16
#define LC (L/NCH)        // 256

// dn = 64^-0.25 = 2^-1.5 ; dn^2*0.5 = 0.0625 ; ratio = 256^-0.5 = 0.0625
#define DNORM 0.35355339059327373f
#define HALF_DN2 0.0625f
#define RATIO 0.0625f

typedef _Float16 f16x8 __attribute__((ext_vector_type(8)));
typedef _Float16 f16x2 __attribute__((ext_vector_type(2)));
typedef float f32x4 __attribute__((ext_vector_type(4)));
typedef unsigned u32x4 __attribute__((ext_vector_type(4)));

// XOR-swizzled LDS index for [col][64 l] fp16 tiles: 8-half blocks permuted by col&7
#define SWZ(col, l) ((col) * 64 + (((l) & 7) | ((((((l) >> 3)) ^ (col)) & 7) << 3)))

__device__ __forceinline__ void gload16(const void* g, void* l) {
    __builtin_amdgcn_global_load_lds((const __attribute__((address_space(1))) unsigned*)g,
                                     (__attribute__((address_space(3))) unsigned*)l, 16, 0, 0);
}

// ---------------- fp32 -> fp16 cast (8 elems/thread) ----------------
__global__ __launch_bounds__(256) void cast_f32_f16(const float* __restrict__ in,
                                                    _Float16* __restrict__ out, int n8) {
    int i = blockIdx.x * 256 + threadIdx.x;
    if (i >= n8) return;
    const float4* p = (const float4*)(in + (size_t)i * 8);
    float4 a = p[0], b = p[1];
    f16x8 o;
    o[0] = (_Float16)a.x; o[1] = (_Float16)a.y; o[2] = (_Float16)a.z; o[3] = (_Float16)a.w;
    o[4] = (_Float16)b.x; o[5] = (_Float16)b.y; o[6] = (_Float16)b.z; o[7] = (_Float16)b.w;
    *(f16x8*)(out + (size_t)i * 8) = o;
}

// ---------------- P fp32 [256][64] -> fp16 FRAGMENT-LINEAR image ----------------
// chunk c = (nf*2+kh)*64 + lane, lane=(kq*16+fr): holds P[nf*16+fr][kh*32+kq*8 + j], j=0..7
__global__ __launch_bounds__(256) void cast_P_frag(const float* __restrict__ P,
                                                   _Float16* __restrict__ Phf) {
    const int t = threadIdx.x;
#pragma unroll
    for (int i = 0; i < 8; i++) {
        const int c = t + i * 256;
        const int f = c >> 6, lane2 = c & 63;
        const int nf = f >> 1, kh = f & 1;
        const int fr = lane2 & 15, kq2 = lane2 >> 4;
        const float* src = P + (nf * 16 + fr) * 64 + kh * 32 + kq2 * 8;
        f16x8 o;
#pragma unroll
        for (int j = 0; j < 8; j++) o[j] = (_Float16)src[j];
        *(f16x8*)(Phf + (size_t)c * 8) = o;
    }
}

// ---------------- fp16 MFMA GEMM:  C[n][o] = sum_k A[n][k] * W[o][k] ----------------
template <typename CT>
__global__ __launch_bounds__(256) void gemm_f16(const _Float16* __restrict__ A,
                                                const _Float16* __restrict__ W,
                                                CT* __restrict__ C,
                                                int N, int K) {
    __shared__ _Float16 As[128 * 32];
    __shared__ _Float16 Bs[128 * 32];
    const int t    = threadIdx.x;
    const int lane = t & 63;
    const int w    = t >> 6;
    const int wr   = w >> 1, wc = w & 1;
    const int brow = blockIdx.y * 128, bcol = blockIdx.x * 128;

    const int c0 = t, c1 = t + 256;
    const _Float16* Ag0 = A + (size_t)(brow + (c0 >> 2)) * K + (c0 & 3) * 8;
    const _Float16* Ag1 = A + (size_t)(brow + (c1 >> 2)) * K + (c1 & 3) * 8;
    const _Float16* Wg0 = W + (size_t)(bcol + (c0 >> 2)) * K + (c0 & 3) * 8;
    const _Float16* Wg1 = W + (size_t)(bcol + (c1 >> 2)) * K + (c1 & 3) * 8;
    _Float16* Al0 = As + c0 * 8;
    _Float16* Al1 = As + c1 * 8;
    _Float16* Bl0 = Bs + c0 * 8;
    _Float16* Bl1 = Bs + c1 * 8;

    f32x4 acc[4][4];
#pragma unroll
    for (int i = 0; i < 4; i++)
#pragma unroll
        for (int j = 0; j < 4; j++) acc[i][j] = (f32x4){0.f, 0.f, 0.f, 0.f};

    const int fr = lane & 15;
    const int kq = lane >> 4;
    const int aoff = (wr * 64 + fr) * 32 + kq * 8;
    const int boff = (wc * 64 + fr) * 32 + kq * 8;

    for (int k0 = 0; k0 < K; k0 += 32) {
        __syncthreads();
        gload16(Ag0 + k0, Al0);
        gload16(Ag1 + k0, Al1);
        gload16(Wg0 + k0, Bl0);
        gload16(Wg1 + k0, Bl1);
        __syncthreads();
        f16x8 af[4], bf[4];
#pragma unroll
        for (int mi = 0; mi < 4; mi++) af[mi] = *(const f16x8*)&As[aoff + mi * 512];
#pragma unroll
        for (int ni = 0; ni < 4; ni++) bf[ni] = *(const f16x8*)&Bs[boff + ni * 512];
#pragma unroll
        for (int mi = 0; mi < 4; mi++)
#pragma unroll
            for (int ni = 0; ni < 4; ni++)
                acc[mi][ni] = __builtin_amdgcn_mfma_f32_16x16x32_f16(af[mi], bf[ni], acc[mi][ni], 0, 0, 0);
    }
#pragma unroll
    for (int mi = 0; mi < 4; mi++) {
#pragma unroll
        for (int ni = 0; ni < 4; ni++) {
            const int row = brow + wr * 64 + mi * 16 + kq * 4;
            const int col = bcol + wc * 64 + ni * 16 + fr;
#pragma unroll
            for (int r = 0; r < 4; r++)
                C[(size_t)(row + r) * N + col] = (CT)acc[mi][ni][r];
        }
    }
}

// ---------------- MFMA phi_k + kv/ksum partials; P from global (L2), ksum via VALU ----------------
// grid (NCH, 64) = 1024 blocks, 4 waves. LDS = 32K phis + 8K vst = 40K.
__global__ __launch_bounds__(256) void kv_kernel3(const _Float16* __restrict__ k,
                                                  const _Float16* __restrict__ v,
                                                  const int* __restrict__ mask,
                                                  const _Float16* __restrict__ Phf,
                                                  float* __restrict__ kvpart,
                                                  float* __restrict__ kspart) {
    const int bh = blockIdx.y, b = bh >> 4, h = bh & 15;
    const int ch = blockIdx.x;
    const int t = threadIdx.x, lane = t & 63, w = t >> 6;
    const int fr = lane & 15, kq = lane >> 4;

    __shared__ _Float16 phis[256 * 64];   // [m][l] swizzled   32KB
    __shared__ _Float16 vst[64 * 64];     // [d][l] swizzled    8KB

    f32x4 acc[4][4];
    float ksacc[4] = {0.f, 0.f, 0.f, 0.f};
#pragma unroll
    for (int mf = 0; mf < 4; mf++)
#pragma unroll
        for (int n2 = 0; n2 < 4; n2++) acc[mf][n2] = (f32x4){0.f, 0.f, 0.f, 0.f};

    const int rr = t & 31, seg = t >> 5;

    for (int tile = 0; tile < LC / 64; ++tile) {
        const int l0 = ch * LC + tile * 64;

        // ---- stage v transposed into vst ----
        {
            const _Float16* v0 = v + (size_t)(b * L + l0 + 2 * rr) * D + h * DK + seg * 8;
            f16x8 a0 = *(const f16x8*)v0;
            f16x8 a1 = *(const f16x8*)(v0 + D);
            if (tile > 0) __syncthreads();   // protect previous tile's LDS reads
#pragma unroll
            for (int j = 0; j < 8; j++) {
                const int d = seg * 8 + j;
                f16x2 pk = {a0[j], a1[j]};
                *(f16x2*)&vst[SWZ(d, 2 * rr)] = pk;
            }
        }

        // ---- phase 1: proj = k @ P^T (k frags + P frags direct from global) ----
        const _Float16* krow = k + (size_t)(b * L + l0 + w * 16 + fr) * D + h * DK + kq * 8;
        f16x8 ak0 = *(const f16x8*)krow;
        f16x8 ak1 = *(const f16x8*)(krow + 32);
        float ns = 0.f;
#pragma unroll
        for (int j = 0; j < 8; j++)
            ns += (float)ak0[j] * (float)ak0[j] + (float)ak1[j] * (float)ak1[j];
        ns += __shfl_xor(ns, 16);
        ns += __shfl_xor(ns, 32);
        ns *= HALF_DN2;

        f32x4 pr[16];
#pragma unroll
        for (int nf = 0; nf < 16; nf++) {
            f16x8 b0 = *(const f16x8*)&Phf[((size_t)(nf * 2 + 0) * 64 + lane) * 8];
            f16x8 b1 = *(const f16x8*)&Phf[((size_t)(nf * 2 + 1) * 64 + lane) * 8];
            f32x4 c = {0.f, 0.f, 0.f, 0.f};
            c = __builtin_amdgcn_mfma_f32_16x16x32_f16(ak0, b0, c, 0, 0, 0);
            c = __builtin_amdgcn_mfma_f32_16x16x32_f16(ak1, b1, c, 0, 0, 0);
            pr[nf] = c;
        }
        float mx[4] = {-1e30f, -1e30f, -1e30f, -1e30f};
#pragma unroll
        for (int nf = 0; nf < 16; nf++)
#pragma unroll
            for (int r = 0; r < 4; r++) {
                pr[nf][r] *= DNORM;
                mx[r] = fmaxf(mx[r], pr[nf][r]);
            }
#pragma unroll
        for (int r = 0; r < 4; r++) {
            mx[r] = fmaxf(mx[r], __shfl_xor(mx[r], 1));
            mx[r] = fmaxf(mx[r], __shfl_xor(mx[r], 2));
            mx[r] = fmaxf(mx[r], __shfl_xor(mx[r], 4));
            mx[r] = fmaxf(mx[r], __shfl_xor(mx[r], 8));
        }
        float sub[4], mkv[4];
#pragma unroll
        for (int r = 0; r < 4; r++) {
            sub[r] = mx[r] + __shfl(ns, kq * 4 + r);
            mkv[r] = (float)mask[b * L + l0 + w * 16 + kq * 4 + r];
        }
#pragma unroll
        for (int nf = 0; nf < 16; nf++) {
            const int col = nf * 16 + fr;
#pragma unroll
            for (int rp = 0; rp < 2; rp++) {
                const int row = w * 16 + kq * 4 + 2 * rp;
                float v0 = mkv[2 * rp]     * (RATIO * (__expf(pr[nf][2 * rp]     - sub[2 * rp])     + 1e-6f));
                float v1 = mkv[2 * rp + 1] * (RATIO * (__expf(pr[nf][2 * rp + 1] - sub[2 * rp + 1]) + 1e-6f));
                f16x2 pk = {(_Float16)v0, (_Float16)v1};
                *(f16x2*)&phis[SWZ(col, row)] = pk;
            }
        }
        __syncthreads();

        // ---- phase 2: acc[m][d] += phi^T @ v^T ; ksum via in-lane sums ----
        f16x8 bfr[4][2];
#pragma unroll
        for (int n2 = 0; n2 < 4; n2++)
#pragma unroll
            for (int ks = 0; ks < 2; ks++)
                bfr[n2][ks] = *(const f16x8*)&vst[SWZ(n2 * 16 + fr, ks * 32 + kq * 8)];
#pragma unroll
        for (int mf = 0; mf < 4; mf++) {
            const int m = w * 64 + mf * 16 + fr;
            f16x8 a0 = *(const f16x8*)&phis[SWZ(m, kq * 8)];
            f16x8 a1 = *(const f16x8*)&phis[SWZ(m, 32 + kq * 8)];
            float sk = 0.f;
#pragma unroll
            for (int j = 0; j < 8; j++) sk += (float)a0[j] + (float)a1[j];
            ksacc[mf] += sk;
#pragma unroll
            for (int n2 = 0; n2 < 4; n2++) {
                acc[mf][n2] = __builtin_amdgcn_mfma_f32_16x16x32_f16(a0, bfr[n2][0], acc[mf][n2], 0, 0, 0);
                acc[mf][n2] = __builtin_amdgcn_mfma_f32_16x16x32_f16(a1, bfr[n2][1], acc[mf][n2], 0, 0, 0);
            }
        }
    }

    // ---- write partials ----
    float* kvp = kvpart + ((size_t)ch * 64 + bh) * M * DK;
    float* ksp = kspart + ((size_t)ch * 64 + bh) * M;
#pragma unroll
    for (int mf = 0; mf < 4; mf++) {
#pragma unroll
        for (int r = 0; r < 4; r++) {
            const int m = w * 64 + mf * 16 + kq * 4 + r;
#pragma unroll
            for (int n2 = 0; n2 < 4; n2++)
                kvp[(size_t)m * DK + n2 * 16 + fr] = acc[mf][n2][r];
        }
        float sk = ksacc[mf];
        sk += __shfl_xor(sk, 16);
        sk += __shfl_xor(sk, 32);
        if (kq == 0) ksp[w * 64 + mf * 16 + fr] = sk;
    }
}

// ---------------- reduce partials -> kvt fp16 FRAGMENT-LINEAR ----------------
// grid (4, 64): block = (d-quarter, bh). kvt[bh][(n2*8+ks)*64 + kq*16+fr][8]; n2=4 -> ksum/zeros
__global__ __launch_bounds__(256) void reduce_kvt2(const float* __restrict__ kvp,
                                                   const float* __restrict__ ksp,
                                                   _Float16* __restrict__ kvt) {
    const int dq = blockIdx.x, bh = blockIdx.y;
    const int t  = threadIdx.x;   // m index
    float s[16];
#pragma unroll
    for (int c = 0; c < 16; c++) s[c] = 0.f;
    for (int ch = 0; ch < NCH; ch++) {
        const float* src = kvp + (((size_t)ch * 64 + bh) * M + t) * DK + dq * 16;
#pragma unroll
        for (int c4 = 0; c4 < 4; c4++) {
            float4 v = *(const float4*)(src + c4 * 4);
            s[c4 * 4 + 0] += v.x; s[c4 * 4 + 1] += v.y;
            s[c4 * 4 + 2] += v.z; s[c4 * 4 + 3] += v.w;
        }
    }
    _Float16* dst = kvt + (size_t)bh * 20480;
    const int ks = t >> 5, kq = (t >> 3) & 3, j = t & 7;
#pragma unroll
    for (int c = 0; c < 16; c++)
        dst[((dq * 8 + ks) * 64 + kq * 16 + c) * 8 + j] = (_Float16)s[c];
    if (dq == 0) {
        float s64 = 0.f;
        for (int ch = 0; ch < NCH; ch++) s64 += ksp[((size_t)ch * 64 + bh) * M + t];
        dst[((4 * 8 + ks) * 64 + kq * 16 + 0) * 8 + j] = (_Float16)s64;
#pragma unroll
        for (int c = 1; c < 16; c++)
            dst[((4 * 8 + ks) * 64 + kq * 16 + c) * 8 + j] = (_Float16)0.f;
    }
}

// ---------------- phi_q + out + denom + normalize; swapped QK, register butterfly ----------------
// grid (L/128, B*H) = (32,16) = 512 blocks, 2 row-tiles of 64. LDS: P 32K + kvs 40K = 72K.
__global__ __launch_bounds__(256) void out_kernel6(const _Float16* __restrict__ q,
                                                   const _Float16* __restrict__ Phf,
                                                   const _Float16* __restrict__ kvtf,
                                                   _Float16* __restrict__ ao) {
    const int bh = blockIdx.y, b = bh >> 4, h = bh & 15;
    const int t = threadIdx.x, lane = t & 63, w = t >> 6;
    const int fr = lane & 15, kq = lane >> 4;

    __shared__ _Float16 Pl[2048 * 8];     // fragment-linear P    32KB
    __shared__ _Float16 kvs[2560 * 8];    // fragment-linear kvt  40KB

    // ---- stage P + kvt once ----
#pragma unroll
    for (int i = 0; i < 8; i++)
        gload16(Phf + (size_t)(t + i * 256) * 8, Pl + (t + i * 256) * 8);
    {
        const _Float16* src = kvtf + (size_t)bh * 20480 + t * 8;
#pragma unroll
        for (int i = 0; i < 10; i++)
            gload16(src + i * 2048, kvs + t * 8 + i * 2048);
    }
    __syncthreads();

    const int srcA = fr + 16 * ((2 * kq) & 3);
    const int srcB = fr + 16 * ((2 * kq + 1) & 3);
    const bool hi  = (kq & 2) != 0;

    for (int rt = 0; rt < 2; ++rt) {
        const int l0 = blockIdx.x * 128 + rt * 64;

        // ---- q fragment (B operand) direct from global + row norm ----
        const _Float16* qp = q + (size_t)(b * L + l0 + w * 16 + fr) * D + h * DK + kq * 8;
        f16x8 aq0 = *(const f16x8*)qp;
        f16x8 aq1 = *(const f16x8*)(qp + 32);
        float ns = 0.f;
#pragma unroll
        for (int j = 0; j < 8; j++)
            ns += (float)aq0[j] * (float)aq0[j] + (float)aq1[j] * (float)aq1[j];
        ns += __shfl_xor(ns, 16);
        ns += __shfl_xor(ns, 32);
        ns *= HALF_DN2;

        // ---- phase 1 (swapped): pr[nf] = P(nf-tile) x q -> C[m][l], col l = fr ----
        f32x4 pr[16];
#pragma unroll
        for (int nf = 0; nf < 16; nf++) {
            f16x8 a0 = *(const f16x8*)&Pl[((nf * 2 + 0) * 64 + lane) * 8];
            f16x8 a1 = *(const f16x8*)&Pl[((nf * 2 + 1) * 64 + lane) * 8];
            f32x4 c = {0.f, 0.f, 0.f, 0.f};
            c = __builtin_amdgcn_mfma_f32_16x16x32_f16(a0, aq0, c, 0, 0, 0);
            c = __builtin_amdgcn_mfma_f32_16x16x32_f16(a1, aq1, c, 0, 0, 0);
            pr[nf] = c;
        }
        float mx = -1e30f;
#pragma unroll
        for (int nf = 0; nf < 16; nf++)
#pragma unroll
            for (int r = 0; r < 4; r++) {
                pr[nf][r] *= DNORM;
                mx = fmaxf(mx, pr[nf][r]);
            }
        mx = fmaxf(mx, __shfl_xor(mx, 16));
        mx = fmaxf(mx, __shfl_xor(mx, 32));
        const float sub = mx + ns;

        // ---- phi + pack to f16x2 (in-register) ----
        unsigned pk_[16][2];
#pragma unroll
        for (int nf = 0; nf < 16; nf++) {
#pragma unroll
            for (int p = 0; p < 2; p++) {
                float v0 = RATIO * (__expf(pr[nf][2 * p]     - sub) + 1e-6f);
                float v1 = RATIO * (__expf(pr[nf][2 * p + 1] - sub) + 1e-6f);
                f16x2 pq = {(_Float16)v0, (_Float16)v1};
                pk_[nf][p] = __builtin_bit_cast(unsigned, pq);
            }
        }

        // ---- phase 2: out[l][d] = phi @ kv^T ; A-frags via butterfly shuffles ----
        f32x4 acc[5];
#pragma unroll
        for (int n2 = 0; n2 < 5; n2++) acc[n2] = (f32x4){0.f, 0.f, 0.f, 0.f};
#pragma unroll
        for (int ks = 0; ks < 8; ks++) {
            unsigned u0 = __shfl(pk_[2 * ks][0], srcA);
            unsigned u1 = __shfl(pk_[2 * ks][1], srcA);
            unsigned u2 = __shfl(pk_[2 * ks][0], srcB);
            unsigned u3 = __shfl(pk_[2 * ks][1], srcB);
            unsigned v0 = __shfl(pk_[2 * ks + 1][0], srcA);
            unsigned v1 = __shfl(pk_[2 * ks + 1][1], srcA);
            unsigned v2 = __shfl(pk_[2 * ks + 1][0], srcB);
            unsigned v3 = __shfl(pk_[2 * ks + 1][1], srcB);
            u32x4 wv;
            wv[0] = hi ? v0 : u0;
            wv[1] = hi ? v1 : u1;
            wv[2] = hi ? v2 : u2;
            wv[3] = hi ? v3 : u3;
            f16x8 af = __builtin_bit_cast(f16x8, wv);
#pragma unroll
            for (int n2 = 0; n2 < 5; n2++) {
                f16x8 bf = *(const f16x8*)&kvs[((n2 * 8 + ks) * 64 + lane) * 8];
                acc[n2] = __builtin_amdgcn_mfma_f32_16x16x32_f16(af, bf, acc[n2], 0, 0, 0);
            }
        }
        // ---- normalize + write ----
#pragma unroll
        for (int r = 0; r < 4; r++) {
            float den = __shfl(acc[4][r], (lane & 48));
            float inv = 1.f / fmaxf(den, 1e-6f);
            const int row = l0 + w * 16 + kq * 4 + r;
            _Float16* dst = ao + (size_t)(b * L + row) * D + h * DK;
#pragma unroll
            for (int n2 = 0; n2 < 4; n2++)
                dst[n2 * 16 + fr] = (_Float16)(acc[n2][r] * inv);
        }
    }
}

extern "C" void kernel_launch(void* const* d_in, const int* in_sizes, int n_in,
                              void* d_out, int out_size, void* d_ws, size_t ws_size,
                              hipStream_t stream) {
    (void)in_sizes; (void)n_in; (void)out_size; (void)ws_size;
    const float* X    = (const float*)d_in[0];
    const int*   mask = (const int*)d_in[1];
    const float* Wq   = (const float*)d_in[2];
    const float* Wk   = (const float*)d_in[3];
    const float* Wv   = (const float*)d_in[4];
    const float* Wo   = (const float*)d_in[5];
    const float* P    = (const float*)d_in[6];

    char* ws = (char*)d_ws;
    // Workspace plan (peak 171.5MB, serial-stream alias-safe):
    _Float16* bufK  = (_Float16*)ws;                      // 0      k, later attn (32M)
    _Float16* bufVQ = (_Float16*)(ws + 33554432);         // 32M    v, later q    (32M)
    _Float16* Xh    = (_Float16*)(ws + 67108864);         // 64M    (32M, live whole run)
    float* kvpart   = (float*)(ws + 100663296);           // 96M    (64M, live kv..reduce)
    _Float16* Wh    = (_Float16*)(ws + 100663296);        //        2M slot ALIASED into kvpart:
                                                          //        Wk/Wv used before kv writes it,
                                                          //        Wq/Wo cast after reduce reads it
    float* kspart   = (float*)(ws + 167772160);           // 160M   (1M)
    _Float16* kvt   = (_Float16*)(ws + 168820736);        //        (2.62M)
    _Float16* Phf   = (_Float16*)(ws + 171442176);        //        (32K) -> end ~171.5M
    float* out      = (float*)d_out;

    dim3 blk(256);
    dim3 gg(8, 128);

    hipLaunchKernelGGL(cast_f32_f16, dim3(8192), blk, 0, stream, X, Xh, 2097152);
    hipLaunchKernelGGL(cast_P_frag, dim3(1), blk, 0, stream, P, Phf);

    hipLaunchKernelGGL(cast_f32_f16, dim3(512), blk, 0, stream, Wk, Wh, 131072);
    hipLaunchKernelGGL((gemm_f16<_Float16>), gg, blk, 0, stream, Xh, Wh, bufK, D, D);
    hipLaunchKernelGGL(cast_f32_f16, dim3(512), blk, 0, stream, Wv, Wh, 131072);
    hipLaunchKernelGGL((gemm_f16<_Float16>), gg, blk, 0, stream, Xh, Wh, bufVQ, D, D);

    hipLaunchKernelGGL(kv_kernel3, dim3(NCH, B * H), blk, 0, stream, bufK, bufVQ, mask, Phf, kvpart, kspart);
    hipLaunchKernelGGL(reduce_kvt2, dim3(4, 64), blk, 0, stream, kvpart, kspart, kvt);

    hipLaunchKernelGGL(cast_f32_f16, dim3(512), blk, 0, stream, Wq, Wh, 131072);
    hipLaunchKernelGGL((gemm_f16<_Float16>), gg, blk, 0, stream, Xh, Wh, bufVQ, D, D);

    hipLaunchKernelGGL(out_kernel6, dim3(L / 128, B * H), blk, 0, stream, bufVQ, Phf, kvt, bufK);

    hipLaunchKernelGGL(cast_f32_f16, dim3(512), blk, 0, stream, Wo, Wh, 131072);
    hipLaunchKernelGGL((gemm_f16<float>), gg, blk, 0, stream, bufK, Wh, out, D, D);
}

// Round 9
// 371.273 us; speedup vs baseline: 1.1600x; 1.1600x over previous
//
#include <hip/hip_runtime.h>
#include <math.h>

#define B 4
#define L 4096
#define D 1024
#define H 16
#define DK 64
#define M 256
#define NTOK (B*L)        // 16384
#define NCH 8
#define LC (L/NCH)        // 512

// dn = 64^-0.25 = 2^-1.5 ; dn^2*0.5 = 0.0625 ; ratio = 256^-0.5 = 0.0625
#define DNORM 0.35355339059327373f
#define HALF_DN2 0.0625f
#define RATIO 0.0625f

typedef _Float16 f16x8 __attribute__((ext_vector_type(8)));
typedef _Float16 f16x2 __attribute__((ext_vector_type(2)));
typedef float f32x4 __attribute__((ext_vector_type(4)));
typedef unsigned u32x4 __attribute__((ext_vector_type(4)));

// XOR-swizzled LDS index for [col][64 l] fp16 tiles: 8-half blocks permuted by col&7
#define SWZ(col, l) ((col) * 64 + (((l) & 7) | ((((((l) >> 3)) ^ (col)) & 7) << 3)))

__device__ __forceinline__ void gload16(const void* g, void* l) {
    __builtin_amdgcn_global_load_lds((const __attribute__((address_space(1))) unsigned*)g,
                                     (__attribute__((address_space(3))) unsigned*)l, 16, 0, 0);
}

// ---------------- fp32 -> fp16 cast (8 elems/thread) ----------------
__global__ __launch_bounds__(256) void cast_f32_f16(const float* __restrict__ in,
                                                    _Float16* __restrict__ out, int n8) {
    int i = blockIdx.x * 256 + threadIdx.x;
    if (i >= n8) return;
    const float4* p = (const float4*)(in + (size_t)i * 8);
    float4 a = p[0], b = p[1];
    f16x8 o;
    o[0] = (_Float16)a.x; o[1] = (_Float16)a.y; o[2] = (_Float16)a.z; o[3] = (_Float16)a.w;
    o[4] = (_Float16)b.x; o[5] = (_Float16)b.y; o[6] = (_Float16)b.z; o[7] = (_Float16)b.w;
    *(f16x8*)(out + (size_t)i * 8) = o;
}

// ---------------- all four W casts in one launch: Wall = [Wk;Wv;Wq;Wo] fp16 ----------------
__global__ __launch_bounds__(256) void cast_w4(const float* __restrict__ Wk,
                                               const float* __restrict__ Wv,
                                               const float* __restrict__ Wq,
                                               const float* __restrict__ Wo,
                                               _Float16* __restrict__ Wall) {
    const int y = blockIdx.y;
    const float* src = (y == 0) ? Wk : (y == 1) ? Wv : (y == 2) ? Wq : Wo;
    const int i = blockIdx.x * 256 + threadIdx.x;   // 131072 chunks of 8 per W
    const float4* p = (const float4*)(src + (size_t)i * 8);
    float4 a = p[0], b = p[1];
    f16x8 o;
    o[0] = (_Float16)a.x; o[1] = (_Float16)a.y; o[2] = (_Float16)a.z; o[3] = (_Float16)a.w;
    o[4] = (_Float16)b.x; o[5] = (_Float16)b.y; o[6] = (_Float16)b.z; o[7] = (_Float16)b.w;
    *(f16x8*)(Wall + (size_t)y * 1048576 + (size_t)i * 8) = o;
}

// ---------------- P fp32 [256][64] -> fp16 FRAGMENT-LINEAR image ----------------
// chunk c = (nf*2+kh)*64 + lane, lane=(kq*16+fr): holds P[nf*16+fr][kh*32+kq*8 + j], j=0..7
__global__ __launch_bounds__(256) void cast_P_frag(const float* __restrict__ P,
                                                   _Float16* __restrict__ Phf) {
    const int t = threadIdx.x;
#pragma unroll
    for (int i = 0; i < 8; i++) {
        const int c = t + i * 256;
        const int f = c >> 6, lane2 = c & 63;
        const int nf = f >> 1, kh = f & 1;
        const int fr = lane2 & 15, kq2 = lane2 >> 4;
        const float* src = P + (nf * 16 + fr) * 64 + kh * 32 + kq2 * 8;
        f16x8 o;
#pragma unroll
        for (int j = 0; j < 8; j++) o[j] = (_Float16)src[j];
        *(f16x8*)(Phf + (size_t)c * 8) = o;
    }
}

// ---------------- fp16 MFMA GEMM:  C[n][o] = sum_k A[n][k] * W[o][k] ----------------
template <typename CT>
__global__ __launch_bounds__(256) void gemm_f16(const _Float16* __restrict__ A,
                                                const _Float16* __restrict__ W,
                                                CT* __restrict__ C,
                                                int N, int K) {
    __shared__ _Float16 As[128 * 32];
    __shared__ _Float16 Bs[128 * 32];
    const int t    = threadIdx.x;
    const int lane = t & 63;
    const int w    = t >> 6;
    const int wr   = w >> 1, wc = w & 1;
    const int brow = blockIdx.y * 128, bcol = blockIdx.x * 128;

    const int c0 = t, c1 = t + 256;
    const _Float16* Ag0 = A + (size_t)(brow + (c0 >> 2)) * K + (c0 & 3) * 8;
    const _Float16* Ag1 = A + (size_t)(brow + (c1 >> 2)) * K + (c1 & 3) * 8;
    const _Float16* Wg0 = W + (size_t)(bcol + (c0 >> 2)) * K + (c0 & 3) * 8;
    const _Float16* Wg1 = W + (size_t)(bcol + (c1 >> 2)) * K + (c1 & 3) * 8;
    _Float16* Al0 = As + c0 * 8;
    _Float16* Al1 = As + c1 * 8;
    _Float16* Bl0 = Bs + c0 * 8;
    _Float16* Bl1 = Bs + c1 * 8;

    f32x4 acc[4][4];
#pragma unroll
    for (int i = 0; i < 4; i++)
#pragma unroll
        for (int j = 0; j < 4; j++) acc[i][j] = (f32x4){0.f, 0.f, 0.f, 0.f};

    const int fr = lane & 15;
    const int kq = lane >> 4;
    const int aoff = (wr * 64 + fr) * 32 + kq * 8;
    const int boff = (wc * 64 + fr) * 32 + kq * 8;

    for (int k0 = 0; k0 < K; k0 += 32) {
        __syncthreads();
        gload16(Ag0 + k0, Al0);
        gload16(Ag1 + k0, Al1);
        gload16(Wg0 + k0, Bl0);
        gload16(Wg1 + k0, Bl1);
        __syncthreads();
        f16x8 af[4], bf[4];
#pragma unroll
        for (int mi = 0; mi < 4; mi++) af[mi] = *(const f16x8*)&As[aoff + mi * 512];
#pragma unroll
        for (int ni = 0; ni < 4; ni++) bf[ni] = *(const f16x8*)&Bs[boff + ni * 512];
#pragma unroll
        for (int mi = 0; mi < 4; mi++)
#pragma unroll
            for (int ni = 0; ni < 4; ni++)
                acc[mi][ni] = __builtin_amdgcn_mfma_f32_16x16x32_f16(af[mi], bf[ni], acc[mi][ni], 0, 0, 0);
    }
#pragma unroll
    for (int mi = 0; mi < 4; mi++) {
#pragma unroll
        for (int ni = 0; ni < 4; ni++) {
            const int row = brow + wr * 64 + mi * 16 + kq * 4;
            const int col = bcol + wc * 64 + ni * 16 + fr;
#pragma unroll
            for (int r = 0; r < 4; r++)
                C[(size_t)(row + r) * N + col] = (CT)acc[mi][ni][r];
        }
    }
}

// ---------------- MFMA phi_k + kv/ksum partials; P staged in LDS once ----------------
// k/v interleaved in kvb: row stride 2048, k at +0, v at +1024.
__global__ __launch_bounds__(256) void kv_kernel2b(const _Float16* __restrict__ kvb,
                                                   const int* __restrict__ mask,
                                                   const _Float16* __restrict__ Phf,
                                                   float* __restrict__ kvpart,
                                                   float* __restrict__ kspart) {
    const int bh = blockIdx.y, b = bh >> 4, h = bh & 15;
    const int ch = blockIdx.x;
    const int t = threadIdx.x, lane = t & 63, w = t >> 6;
    const int fr = lane & 15, kq = lane >> 4;

    __shared__ _Float16 phis[256 * 64];   // [m][l] swizzled          32KB
    __shared__ _Float16 vst[80 * 64];     // [d][l] swizzled; row64=1 10KB
    __shared__ _Float16 Pl[256 * 64];     // fragment-linear P image  32KB

    // ---- stage P once (linear gload from frag-linear global) ----
#pragma unroll
    for (int i = 0; i < 8; i++)
        gload16(Phf + (size_t)(t + i * 256) * 8, Pl + (t + i * 256) * 8);

    if (t < 128) {
        const int row = 64 + (t >> 3), off = (t & 7) * 8;
        const _Float16 val = (row == 64) ? (_Float16)1.0f : (_Float16)0.0f;
        f16x8 o = {val, val, val, val, val, val, val, val};
        *(f16x8*)&vst[row * 64 + off] = o;
    }
    __syncthreads();   // Pl staged, vst rows 64.. ready

    f32x4 acc[4][5];
#pragma unroll
    for (int mf = 0; mf < 4; mf++)
#pragma unroll
        for (int n2 = 0; n2 < 5; n2++) acc[mf][n2] = (f32x4){0.f, 0.f, 0.f, 0.f};

    const int rr = t & 31, seg = t >> 5;

    for (int tile = 0; tile < LC / 64; ++tile) {
        const int l0 = ch * LC + tile * 64;

        {
            const _Float16* v0 = kvb + (size_t)(b * L + l0 + 2 * rr) * 2048 + 1024 + h * DK + seg * 8;
            f16x8 a0 = *(const f16x8*)v0;
            f16x8 a1 = *(const f16x8*)(v0 + 2048);
#pragma unroll
            for (int j = 0; j < 8; j++) {
                const int d = seg * 8 + j;
                f16x2 pk = {a0[j], a1[j]};
                *(f16x2*)&vst[SWZ(d, 2 * rr)] = pk;
            }
        }

        const _Float16* krow = kvb + (size_t)(b * L + l0 + w * 16 + fr) * 2048 + h * DK + kq * 8;
        f16x8 ak0 = *(const f16x8*)krow;
        f16x8 ak1 = *(const f16x8*)(krow + 32);
        float ns = 0.f;
#pragma unroll
        for (int j = 0; j < 8; j++)
            ns += (float)ak0[j] * (float)ak0[j] + (float)ak1[j] * (float)ak1[j];
        ns += __shfl_xor(ns, 16);
        ns += __shfl_xor(ns, 32);
        ns *= HALF_DN2;

        f32x4 pr[16];
#pragma unroll
        for (int nf = 0; nf < 16; nf++) {
            f16x8 b0 = *(const f16x8*)&Pl[((nf * 2 + 0) * 64 + lane) * 8];
            f16x8 b1 = *(const f16x8*)&Pl[((nf * 2 + 1) * 64 + lane) * 8];
            f32x4 c = {0.f, 0.f, 0.f, 0.f};
            c = __builtin_amdgcn_mfma_f32_16x16x32_f16(ak0, b0, c, 0, 0, 0);
            c = __builtin_amdgcn_mfma_f32_16x16x32_f16(ak1, b1, c, 0, 0, 0);
            pr[nf] = c;
        }
        float mx[4] = {-1e30f, -1e30f, -1e30f, -1e30f};
#pragma unroll
        for (int nf = 0; nf < 16; nf++)
#pragma unroll
            for (int r = 0; r < 4; r++) {
                pr[nf][r] *= DNORM;
                mx[r] = fmaxf(mx[r], pr[nf][r]);
            }
#pragma unroll
        for (int r = 0; r < 4; r++) {
            mx[r] = fmaxf(mx[r], __shfl_xor(mx[r], 1));
            mx[r] = fmaxf(mx[r], __shfl_xor(mx[r], 2));
            mx[r] = fmaxf(mx[r], __shfl_xor(mx[r], 4));
            mx[r] = fmaxf(mx[r], __shfl_xor(mx[r], 8));
        }
        float sub[4], mkv[4];
#pragma unroll
        for (int r = 0; r < 4; r++) {
            sub[r] = mx[r] + __shfl(ns, kq * 4 + r);
            mkv[r] = (float)mask[b * L + l0 + w * 16 + kq * 4 + r];
        }
#pragma unroll
        for (int nf = 0; nf < 16; nf++) {
            const int col = nf * 16 + fr;
#pragma unroll
            for (int rp = 0; rp < 2; rp++) {
                const int row = w * 16 + kq * 4 + 2 * rp;
                float v0 = mkv[2 * rp]     * (RATIO * (__expf(pr[nf][2 * rp]     - sub[2 * rp])     + 1e-6f));
                float v1 = mkv[2 * rp + 1] * (RATIO * (__expf(pr[nf][2 * rp + 1] - sub[2 * rp + 1]) + 1e-6f));
                f16x2 pk = {(_Float16)v0, (_Float16)v1};
                *(f16x2*)&phis[SWZ(col, row)] = pk;
            }
        }
        __syncthreads();

        f16x8 bfr[5][2];
#pragma unroll
        for (int n2 = 0; n2 < 5; n2++)
#pragma unroll
            for (int ks = 0; ks < 2; ks++)
                bfr[n2][ks] = *(const f16x8*)&vst[SWZ(n2 * 16 + fr, ks * 32 + kq * 8)];
#pragma unroll
        for (int mf = 0; mf < 4; mf++) {
            const int m = w * 64 + mf * 16 + fr;
            f16x8 a0 = *(const f16x8*)&phis[SWZ(m, kq * 8)];
            f16x8 a1 = *(const f16x8*)&phis[SWZ(m, 32 + kq * 8)];
#pragma unroll
            for (int n2 = 0; n2 < 5; n2++) {
                acc[mf][n2] = __builtin_amdgcn_mfma_f32_16x16x32_f16(a0, bfr[n2][0], acc[mf][n2], 0, 0, 0);
                acc[mf][n2] = __builtin_amdgcn_mfma_f32_16x16x32_f16(a1, bfr[n2][1], acc[mf][n2], 0, 0, 0);
            }
        }
        __syncthreads();
    }

    float* kvp = kvpart + ((size_t)ch * 64 + bh) * M * DK;
    float* ksp = kspart + ((size_t)ch * 64 + bh) * M;
#pragma unroll
    for (int mf = 0; mf < 4; mf++) {
#pragma unroll
        for (int r = 0; r < 4; r++) {
            const int m = w * 64 + mf * 16 + kq * 4 + r;
#pragma unroll
            for (int n2 = 0; n2 < 4; n2++)
                kvp[(size_t)m * DK + n2 * 16 + fr] = acc[mf][n2][r];
            if (fr == 0) ksp[m] = acc[mf][4][r];
        }
    }
}

// ---------------- reduce partials -> kvt fp16 FRAGMENT-LINEAR ----------------
// grid (4, 64): block = (d-quarter, bh). kvt[bh][(n2*8+ks)*64 + kq*16+fr][8]; n2=4 -> ksum/zeros
__global__ __launch_bounds__(256) void reduce_kvt2(const float* __restrict__ kvp,
                                                   const float* __restrict__ ksp,
                                                   _Float16* __restrict__ kvt) {
    const int dq = blockIdx.x, bh = blockIdx.y;
    const int t  = threadIdx.x;   // m index
    float s[16];
#pragma unroll
    for (int c = 0; c < 16; c++) s[c] = 0.f;
    for (int ch = 0; ch < NCH; ch++) {
        const float* src = kvp + (((size_t)ch * 64 + bh) * M + t) * DK + dq * 16;
#pragma unroll
        for (int c4 = 0; c4 < 4; c4++) {
            float4 v = *(const float4*)(src + c4 * 4);
            s[c4 * 4 + 0] += v.x; s[c4 * 4 + 1] += v.y;
            s[c4 * 4 + 2] += v.z; s[c4 * 4 + 3] += v.w;
        }
    }
    _Float16* dst = kvt + (size_t)bh * 20480;
    const int ks = t >> 5, kq = (t >> 3) & 3, j = t & 7;
#pragma unroll
    for (int c = 0; c < 16; c++)
        dst[((dq * 8 + ks) * 64 + kq * 16 + c) * 8 + j] = (_Float16)s[c];
    if (dq == 0) {
        float s64 = 0.f;
        for (int ch = 0; ch < NCH; ch++) s64 += ksp[((size_t)ch * 64 + bh) * M + t];
        dst[((4 * 8 + ks) * 64 + kq * 16 + 0) * 8 + j] = (_Float16)s64;
#pragma unroll
        for (int c = 1; c < 16; c++)
            dst[((4 * 8 + ks) * 64 + kq * 16 + c) * 8 + j] = (_Float16)0.f;
    }
}

// ---------------- phi_q + out + denom + normalize; swapped QK, register butterfly ----------------
// grid (L/128, B*H) = (32,16), 2 row-tiles of 64. LDS: kvs 40K only (P frags from global/L2).
__global__ __launch_bounds__(256) void out_kernel7(const _Float16* __restrict__ q,
                                                   const _Float16* __restrict__ Phf,
                                                   const _Float16* __restrict__ kvtf,
                                                   _Float16* __restrict__ ao) {
    const int bh = blockIdx.y, b = bh >> 4, h = bh & 15;
    const int t = threadIdx.x, lane = t & 63, w = t >> 6;
    const int fr = lane & 15, kq = lane >> 4;

    __shared__ _Float16 kvs[2560 * 8];    // fragment-linear kvt  40KB

    // ---- stage kvt once ----
    {
        const _Float16* src = kvtf + (size_t)bh * 20480 + t * 8;
#pragma unroll
        for (int i = 0; i < 10; i++)
            gload16(src + i * 2048, kvs + t * 8 + i * 2048);
    }
    __syncthreads();

    const int srcA = fr + 16 * ((2 * kq) & 3);
    const int srcB = fr + 16 * ((2 * kq + 1) & 3);
    const bool hi  = (kq & 2) != 0;

    for (int rt = 0; rt < 2; ++rt) {
        const int l0 = blockIdx.x * 128 + rt * 64;

        // ---- q fragment (B operand) direct from global + row norm ----
        const _Float16* qp = q + (size_t)(b * L + l0 + w * 16 + fr) * D + h * DK + kq * 8;
        f16x8 aq0 = *(const f16x8*)qp;
        f16x8 aq1 = *(const f16x8*)(qp + 32);
        float ns = 0.f;
#pragma unroll
        for (int j = 0; j < 8; j++)
            ns += (float)aq0[j] * (float)aq0[j] + (float)aq1[j] * (float)aq1[j];
        ns += __shfl_xor(ns, 16);
        ns += __shfl_xor(ns, 32);
        ns *= HALF_DN2;

        // ---- phase 1 (swapped): pr[nf] = P(nf-tile) x q -> C[m][l], col l = fr ----
        f32x4 pr[16];
#pragma unroll
        for (int nf = 0; nf < 16; nf++) {
            f16x8 a0 = *(const f16x8*)&Phf[((size_t)(nf * 2 + 0) * 64 + lane) * 8];
            f16x8 a1 = *(const f16x8*)&Phf[((size_t)(nf * 2 + 1) * 64 + lane) * 8];
            f32x4 c = {0.f, 0.f, 0.f, 0.f};
            c = __builtin_amdgcn_mfma_f32_16x16x32_f16(a0, aq0, c, 0, 0, 0);
            c = __builtin_amdgcn_mfma_f32_16x16x32_f16(a1, aq1, c, 0, 0, 0);
            pr[nf] = c;
        }
        float mx = -1e30f;
#pragma unroll
        for (int nf = 0; nf < 16; nf++)
#pragma unroll
            for (int r = 0; r < 4; r++) {
                pr[nf][r] *= DNORM;
                mx = fmaxf(mx, pr[nf][r]);
            }
        mx = fmaxf(mx, __shfl_xor(mx, 16));
        mx = fmaxf(mx, __shfl_xor(mx, 32));
        const float sub = mx + ns;

        // ---- phi + pack to f16x2 (in-register) ----
        unsigned pk_[16][2];
#pragma unroll
        for (int nf = 0; nf < 16; nf++) {
#pragma unroll
            for (int p = 0; p < 2; p++) {
                float v0 = RATIO * (__expf(pr[nf][2 * p]     - sub) + 1e-6f);
                float v1 = RATIO * (__expf(pr[nf][2 * p + 1] - sub) + 1e-6f);
                f16x2 pq = {(_Float16)v0, (_Float16)v1};
                pk_[nf][p] = __builtin_bit_cast(unsigned, pq);
            }
        }

        // ---- phase 2: out[l][d] = phi @ kv^T ; A-frags via butterfly shuffles ----
        f32x4 acc[5];
#pragma unroll
        for (int n2 = 0; n2 < 5; n2++) acc[n2] = (f32x4){0.f, 0.f, 0.f, 0.f};
#pragma unroll
        for (int ks = 0; ks < 8; ks++) {
            unsigned u0 = __shfl(pk_[2 * ks][0], srcA);
            unsigned u1 = __shfl(pk_[2 * ks][1], srcA);
            unsigned u2 = __shfl(pk_[2 * ks][0], srcB);
            unsigned u3 = __shfl(pk_[2 * ks][1], srcB);
            unsigned v0 = __shfl(pk_[2 * ks + 1][0], srcA);
            unsigned v1 = __shfl(pk_[2 * ks + 1][1], srcA);
            unsigned v2 = __shfl(pk_[2 * ks + 1][0], srcB);
            unsigned v3 = __shfl(pk_[2 * ks + 1][1], srcB);
            u32x4 wv;
            wv[0] = hi ? v0 : u0;
            wv[1] = hi ? v1 : u1;
            wv[2] = hi ? v2 : u2;
            wv[3] = hi ? v3 : u3;
            f16x8 af = __builtin_bit_cast(f16x8, wv);
#pragma unroll
            for (int n2 = 0; n2 < 5; n2++) {
                f16x8 bf = *(const f16x8*)&kvs[((n2 * 8 + ks) * 64 + lane) * 8];
                acc[n2] = __builtin_amdgcn_mfma_f32_16x16x32_f16(af, bf, acc[n2], 0, 0, 0);
            }
        }
        // ---- normalize + write ----
#pragma unroll
        for (int r = 0; r < 4; r++) {
            float den = __shfl(acc[4][r], (lane & 48));
            float inv = 1.f / fmaxf(den, 1e-6f);
            const int row = l0 + w * 16 + kq * 4 + r;
            _Float16* dst = ao + (size_t)(b * L + row) * D + h * DK;
#pragma unroll
            for (int n2 = 0; n2 < 4; n2++)
                dst[n2 * 16 + fr] = (_Float16)(acc[n2][r] * inv);
        }
    }
}

extern "C" void kernel_launch(void* const* d_in, const int* in_sizes, int n_in,
                              void* d_out, int out_size, void* d_ws, size_t ws_size,
                              hipStream_t stream) {
    (void)in_sizes; (void)n_in; (void)out_size; (void)ws_size;
    const float* X    = (const float*)d_in[0];
    const int*   mask = (const int*)d_in[1];
    const float* Wq   = (const float*)d_in[2];
    const float* Wk   = (const float*)d_in[3];
    const float* Wv   = (const float*)d_in[4];
    const float* Wo   = (const float*)d_in[5];
    const float* P    = (const float*)d_in[6];

    char* ws = (char*)d_ws;
    // Workspace (total 145,784,832 B = round-6 proven extent):
    _Float16* Xh    = (_Float16*)ws;                      // 0..32M
    _Float16* kvb   = (_Float16*)(ws + 33554432);         // 32M..96M  [k|v] stride 2048
    _Float16* attn  = (_Float16*)(ws + 33554432);         // reuses dead k-half after kv_kernel
    _Float16* bufQ  = (_Float16*)(ws + 67108864);         // reuses dead v-half after kv_kernel
    float* kvpart   = (float*)(ws + 100663296);           // 32MB
    float* kspart   = (float*)(ws + 134217728);           // 512KB
    _Float16* kvt   = (_Float16*)(ws + 134742016);        // 2.62MB
    _Float16* Wall  = (_Float16*)(ws + 137363456);        // 8MB [Wk;Wv;Wq;Wo]
    _Float16* Phf   = (_Float16*)(ws + 145752064);        // 32KB
    float* out      = (float*)d_out;

    dim3 blk(256);
    hipLaunchKernelGGL(cast_f32_f16, dim3(8192), blk, 0, stream, X, Xh, 2097152);
    hipLaunchKernelGGL(cast_w4, dim3(512, 4), blk, 0, stream, Wk, Wv, Wq, Wo, Wall);
    hipLaunchKernelGGL(cast_P_frag, dim3(1), blk, 0, stream, P, Phf);

    // K+V fused projection: C[16384][2048] = Xh @ [Wk;Wv]^T
    hipLaunchKernelGGL((gemm_f16<_Float16>), dim3(16, 128), blk, 0, stream, Xh, Wall, kvb, 2048, D);

    hipLaunchKernelGGL(kv_kernel2b, dim3(NCH, B * H), blk, 0, stream, kvb, mask, Phf, kvpart, kspart);
    hipLaunchKernelGGL(reduce_kvt2, dim3(4, 64), blk, 0, stream, kvpart, kspart, kvt);

    // Q projection (into dead v-half)
    hipLaunchKernelGGL((gemm_f16<_Float16>), dim3(8, 128), blk, 0, stream, Xh, Wall + 2 * 1048576, bufQ, D, D);

    hipLaunchKernelGGL(out_kernel7, dim3(L / 128, B * H), blk, 0, stream, bufQ, Phf, kvt, attn);

    hipLaunchKernelGGL((gemm_f16<float>), dim3(8, 128), blk, 0, stream, attn, Wall + 3 * 1048576, out, D, D);
}

// Round 10
// 335.525 us; speedup vs baseline: 1.2836x; 1.1065x over previous
//
#include <hip/hip_runtime.h>
#include <math.h>

#define B 4
#define L 4096
#define D 1024
#define H 16
#define DK 64
#define M 256
#define NTOK (B*L)        // 16384
#define NCH 8
#define LC (L/NCH)        // 512

// dn = 64^-0.25 = 2^-1.5 ; dn^2*0.5 = 0.0625 ; ratio = 256^-0.5 = 0.0625
#define DNORM 0.35355339059327373f
#define HALF_DN2 0.0625f
#define RATIO 0.0625f

typedef _Float16 f16x8 __attribute__((ext_vector_type(8)));
typedef _Float16 f16x2 __attribute__((ext_vector_type(2)));
typedef float f32x4 __attribute__((ext_vector_type(4)));
typedef unsigned u32x4 __attribute__((ext_vector_type(4)));

// XOR-swizzled LDS index for [col][64 l] fp16 tiles: 8-half blocks permuted by col&7
#define SWZ(col, l) ((col) * 64 + (((l) & 7) | ((((((l) >> 3)) ^ (col)) & 7) << 3)))

__device__ __forceinline__ void gload16(const void* g, void* l) {
    __builtin_amdgcn_global_load_lds((const __attribute__((address_space(1))) unsigned*)g,
                                     (__attribute__((address_space(3))) unsigned*)l, 16, 0, 0);
}

// ---------------- fp32 -> fp16 cast (8 elems/thread) ----------------
__global__ __launch_bounds__(256) void cast_f32_f16(const float* __restrict__ in,
                                                    _Float16* __restrict__ out, int n8) {
    int i = blockIdx.x * 256 + threadIdx.x;
    if (i >= n8) return;
    const float4* p = (const float4*)(in + (size_t)i * 8);
    float4 a = p[0], b = p[1];
    f16x8 o;
    o[0] = (_Float16)a.x; o[1] = (_Float16)a.y; o[2] = (_Float16)a.z; o[3] = (_Float16)a.w;
    o[4] = (_Float16)b.x; o[5] = (_Float16)b.y; o[6] = (_Float16)b.z; o[7] = (_Float16)b.w;
    *(f16x8*)(out + (size_t)i * 8) = o;
}

// ---------------- all four W casts in one launch: Wall = [Wk;Wv;Wq;Wo] fp16 ----------------
__global__ __launch_bounds__(256) void cast_w4(const float* __restrict__ Wk,
                                               const float* __restrict__ Wv,
                                               const float* __restrict__ Wq,
                                               const float* __restrict__ Wo,
                                               _Float16* __restrict__ Wall) {
    const int y = blockIdx.y;
    const float* src = (y == 0) ? Wk : (y == 1) ? Wv : (y == 2) ? Wq : Wo;
    const int i = blockIdx.x * 256 + threadIdx.x;
    const float4* p = (const float4*)(src + (size_t)i * 8);
    float4 a = p[0], b = p[1];
    f16x8 o;
    o[0] = (_Float16)a.x; o[1] = (_Float16)a.y; o[2] = (_Float16)a.z; o[3] = (_Float16)a.w;
    o[4] = (_Float16)b.x; o[5] = (_Float16)b.y; o[6] = (_Float16)b.z; o[7] = (_Float16)b.w;
    *(f16x8*)(Wall + (size_t)y * 1048576 + (size_t)i * 8) = o;
}

// ---------------- P fp32 [256][64] -> fp16 FRAGMENT-LINEAR image ----------------
// chunk c = (nf*2+kh)*64 + lane, lane=(kq*16+fr): holds P[nf*16+fr][kh*32+kq*8 + j], j=0..7
__global__ __launch_bounds__(256) void cast_P_frag(const float* __restrict__ P,
                                                   _Float16* __restrict__ Phf) {
    const int t = threadIdx.x;
#pragma unroll
    for (int i = 0; i < 8; i++) {
        const int c = t + i * 256;
        const int f = c >> 6, lane2 = c & 63;
        const int nf = f >> 1, kh = f & 1;
        const int fr = lane2 & 15, kq2 = lane2 >> 4;
        const float* src = P + (nf * 16 + fr) * 64 + kh * 32 + kq2 * 8;
        f16x8 o;
#pragma unroll
        for (int j = 0; j < 8; j++) o[j] = (_Float16)src[j];
        *(f16x8*)(Phf + (size_t)c * 8) = o;
    }
}

// ---------------- fp16 MFMA GEMM, BK=64, XOR-swizzled LDS:  C[n][o] = sum_k A[n][k]*W[o][k] ----------------
// LDS slot p of row r holds source chunk (p ^ (r&7)); staged via pre-swizzled global source
// (rule #21: linear gload_lds dest + permuted source + swizzled read). Conflict-free ds_read_b128.
template <typename CT>
__global__ __launch_bounds__(256) void gemm_f16(const _Float16* __restrict__ A,
                                                const _Float16* __restrict__ W,
                                                CT* __restrict__ C,
                                                int N, int K) {
    __shared__ _Float16 As[128 * 64];
    __shared__ _Float16 Bs[128 * 64];
    const int t    = threadIdx.x;
    const int lane = t & 63;
    const int w    = t >> 6;
    const int wr   = w >> 1, wc = w & 1;
    const int brow = blockIdx.y * 128, bcol = blockIdx.x * 128;
    const int fr = lane & 15;
    const int kq = lane >> 4;

    // staging map: LDS chunk c holds source chunk (c&7)^(rc&7) of row rc=c>>3
    int srow[4], soff[4];
#pragma unroll
    for (int i = 0; i < 4; i++) {
        const int c = t + i * 256;
        srow[i] = c >> 3;
        soff[i] = ((c & 7) ^ ((c >> 3) & 7)) * 8;
    }

    f32x4 acc[4][4];
#pragma unroll
    for (int i = 0; i < 4; i++)
#pragma unroll
        for (int j = 0; j < 4; j++) acc[i][j] = (f32x4){0.f, 0.f, 0.f, 0.f};

    for (int k0 = 0; k0 < K; k0 += 64) {
        __syncthreads();
#pragma unroll
        for (int i = 0; i < 4; i++) {
            const int c = t + i * 256;
            gload16(A + (size_t)(brow + srow[i]) * K + k0 + soff[i], As + c * 8);
            gload16(W + (size_t)(bcol + srow[i]) * K + k0 + soff[i], Bs + c * 8);
        }
        __syncthreads();
#pragma unroll
        for (int kh = 0; kh < 2; kh++) {
            f16x8 af[4], bf[4];
#pragma unroll
            for (int mi = 0; mi < 4; mi++) {
                const int row = wr * 64 + mi * 16 + fr;
                af[mi] = *(const f16x8*)&As[row * 64 + (((kh * 4 + kq) ^ (row & 7)) << 3)];
            }
#pragma unroll
            for (int ni = 0; ni < 4; ni++) {
                const int row = wc * 64 + ni * 16 + fr;
                bf[ni] = *(const f16x8*)&Bs[row * 64 + (((kh * 4 + kq) ^ (row & 7)) << 3)];
            }
#pragma unroll
            for (int mi = 0; mi < 4; mi++)
#pragma unroll
                for (int ni = 0; ni < 4; ni++)
                    acc[mi][ni] = __builtin_amdgcn_mfma_f32_16x16x32_f16(af[mi], bf[ni], acc[mi][ni], 0, 0, 0);
        }
    }
#pragma unroll
    for (int mi = 0; mi < 4; mi++) {
#pragma unroll
        for (int ni = 0; ni < 4; ni++) {
            const int row = brow + wr * 64 + mi * 16 + kq * 4;
            const int col = bcol + wc * 64 + ni * 16 + fr;
#pragma unroll
            for (int r = 0; r < 4; r++)
                C[(size_t)(row + r) * N + col] = (CT)acc[mi][ni][r];
        }
    }
}

// ---------------- MFMA phi_k + kv/ksum partials; P frags from global (L2-resident) ----------------
// k/v interleaved in kvb: row stride 2048, k at +0, v at +1024. LDS 42KB -> 3 blocks/CU.
__global__ __launch_bounds__(256) void kv_kernel4(const _Float16* __restrict__ kvb,
                                                  const int* __restrict__ mask,
                                                  const _Float16* __restrict__ Phf,
                                                  float* __restrict__ kvpart,
                                                  float* __restrict__ kspart) {
    const int bh = blockIdx.y, b = bh >> 4, h = bh & 15;
    const int ch = blockIdx.x;
    const int t = threadIdx.x, lane = t & 63, w = t >> 6;
    const int fr = lane & 15, kq = lane >> 4;

    __shared__ _Float16 phis[256 * 64];   // [m][l] swizzled          32KB
    __shared__ _Float16 vst[80 * 64];     // [d][l] swizzled; row64=1 10KB

    if (t < 128) {
        const int row = 64 + (t >> 3), off = (t & 7) * 8;
        const _Float16 val = (row == 64) ? (_Float16)1.0f : (_Float16)0.0f;
        f16x8 o = {val, val, val, val, val, val, val, val};
        *(f16x8*)&vst[row * 64 + off] = o;
    }
    __syncthreads();

    f32x4 acc[4][5];
#pragma unroll
    for (int mf = 0; mf < 4; mf++)
#pragma unroll
        for (int n2 = 0; n2 < 5; n2++) acc[mf][n2] = (f32x4){0.f, 0.f, 0.f, 0.f};

    const int rr = t & 31, seg = t >> 5;

    for (int tile = 0; tile < LC / 64; ++tile) {
        const int l0 = ch * LC + tile * 64;

        {
            const _Float16* v0 = kvb + (size_t)(b * L + l0 + 2 * rr) * 2048 + 1024 + h * DK + seg * 8;
            f16x8 a0 = *(const f16x8*)v0;
            f16x8 a1 = *(const f16x8*)(v0 + 2048);
#pragma unroll
            for (int j = 0; j < 8; j++) {
                const int d = seg * 8 + j;
                f16x2 pk = {a0[j], a1[j]};
                *(f16x2*)&vst[SWZ(d, 2 * rr)] = pk;
            }
        }

        const _Float16* krow = kvb + (size_t)(b * L + l0 + w * 16 + fr) * 2048 + h * DK + kq * 8;
        f16x8 ak0 = *(const f16x8*)krow;
        f16x8 ak1 = *(const f16x8*)(krow + 32);
        float ns = 0.f;
#pragma unroll
        for (int j = 0; j < 8; j++)
            ns += (float)ak0[j] * (float)ak0[j] + (float)ak1[j] * (float)ak1[j];
        ns += __shfl_xor(ns, 16);
        ns += __shfl_xor(ns, 32);
        ns *= HALF_DN2;

        f32x4 pr[16];
#pragma unroll
        for (int nf = 0; nf < 16; nf++) {
            f16x8 b0 = *(const f16x8*)&Phf[((size_t)(nf * 2 + 0) * 64 + lane) * 8];
            f16x8 b1 = *(const f16x8*)&Phf[((size_t)(nf * 2 + 1) * 64 + lane) * 8];
            f32x4 c = {0.f, 0.f, 0.f, 0.f};
            c = __builtin_amdgcn_mfma_f32_16x16x32_f16(ak0, b0, c, 0, 0, 0);
            c = __builtin_amdgcn_mfma_f32_16x16x32_f16(ak1, b1, c, 0, 0, 0);
            pr[nf] = c;
        }
        float mx[4] = {-1e30f, -1e30f, -1e30f, -1e30f};
#pragma unroll
        for (int nf = 0; nf < 16; nf++)
#pragma unroll
            for (int r = 0; r < 4; r++) {
                pr[nf][r] *= DNORM;
                mx[r] = fmaxf(mx[r], pr[nf][r]);
            }
#pragma unroll
        for (int r = 0; r < 4; r++) {
            mx[r] = fmaxf(mx[r], __shfl_xor(mx[r], 1));
            mx[r] = fmaxf(mx[r], __shfl_xor(mx[r], 2));
            mx[r] = fmaxf(mx[r], __shfl_xor(mx[r], 4));
            mx[r] = fmaxf(mx[r], __shfl_xor(mx[r], 8));
        }
        float sub[4], mkv[4];
#pragma unroll
        for (int r = 0; r < 4; r++) {
            sub[r] = mx[r] + __shfl(ns, kq * 4 + r);
            mkv[r] = (float)mask[b * L + l0 + w * 16 + kq * 4 + r];
        }
#pragma unroll
        for (int nf = 0; nf < 16; nf++) {
            const int col = nf * 16 + fr;
#pragma unroll
            for (int rp = 0; rp < 2; rp++) {
                const int row = w * 16 + kq * 4 + 2 * rp;
                float v0 = mkv[2 * rp]     * (RATIO * (__expf(pr[nf][2 * rp]     - sub[2 * rp])     + 1e-6f));
                float v1 = mkv[2 * rp + 1] * (RATIO * (__expf(pr[nf][2 * rp + 1] - sub[2 * rp + 1]) + 1e-6f));
                f16x2 pk = {(_Float16)v0, (_Float16)v1};
                *(f16x2*)&phis[SWZ(col, row)] = pk;
            }
        }
        __syncthreads();

        f16x8 bfr[5][2];
#pragma unroll
        for (int n2 = 0; n2 < 5; n2++)
#pragma unroll
            for (int ks = 0; ks < 2; ks++)
                bfr[n2][ks] = *(const f16x8*)&vst[SWZ(n2 * 16 + fr, ks * 32 + kq * 8)];
#pragma unroll
        for (int mf = 0; mf < 4; mf++) {
            const int m = w * 64 + mf * 16 + fr;
            f16x8 a0 = *(const f16x8*)&phis[SWZ(m, kq * 8)];
            f16x8 a1 = *(const f16x8*)&phis[SWZ(m, 32 + kq * 8)];
#pragma unroll
            for (int n2 = 0; n2 < 5; n2++) {
                acc[mf][n2] = __builtin_amdgcn_mfma_f32_16x16x32_f16(a0, bfr[n2][0], acc[mf][n2], 0, 0, 0);
                acc[mf][n2] = __builtin_amdgcn_mfma_f32_16x16x32_f16(a1, bfr[n2][1], acc[mf][n2], 0, 0, 0);
            }
        }
        __syncthreads();
    }

    float* kvp = kvpart + ((size_t)ch * 64 + bh) * M * DK;
    float* ksp = kspart + ((size_t)ch * 64 + bh) * M;
#pragma unroll
    for (int mf = 0; mf < 4; mf++) {
#pragma unroll
        for (int r = 0; r < 4; r++) {
            const int m = w * 64 + mf * 16 + kq * 4 + r;
#pragma unroll
            for (int n2 = 0; n2 < 4; n2++)
                kvp[(size_t)m * DK + n2 * 16 + fr] = acc[mf][n2][r];
            if (fr == 0) ksp[m] = acc[mf][4][r];
        }
    }
}

// ---------------- reduce partials -> kvt fp16 FRAGMENT-LINEAR ----------------
// grid (4, 64): block = (d-quarter, bh). kvt[bh][(n2*8+ks)*64 + kq*16+fr][8]; n2=4 -> ksum/zeros
__global__ __launch_bounds__(256) void reduce_kvt2(const float* __restrict__ kvp,
                                                   const float* __restrict__ ksp,
                                                   _Float16* __restrict__ kvt) {
    const int dq = blockIdx.x, bh = blockIdx.y;
    const int t  = threadIdx.x;   // m index
    float s[16];
#pragma unroll
    for (int c = 0; c < 16; c++) s[c] = 0.f;
    for (int ch = 0; ch < NCH; ch++) {
        const float* src = kvp + (((size_t)ch * 64 + bh) * M + t) * DK + dq * 16;
#pragma unroll
        for (int c4 = 0; c4 < 4; c4++) {
            float4 v = *(const float4*)(src + c4 * 4);
            s[c4 * 4 + 0] += v.x; s[c4 * 4 + 1] += v.y;
            s[c4 * 4 + 2] += v.z; s[c4 * 4 + 3] += v.w;
        }
    }
    _Float16* dst = kvt + (size_t)bh * 20480;
    const int ks = t >> 5, kq = (t >> 3) & 3, j = t & 7;
#pragma unroll
    for (int c = 0; c < 16; c++)
        dst[((dq * 8 + ks) * 64 + kq * 16 + c) * 8 + j] = (_Float16)s[c];
    if (dq == 0) {
        float s64 = 0.f;
        for (int ch = 0; ch < NCH; ch++) s64 += ksp[((size_t)ch * 64 + bh) * M + t];
        dst[((4 * 8 + ks) * 64 + kq * 16 + 0) * 8 + j] = (_Float16)s64;
#pragma unroll
        for (int c = 1; c < 16; c++)
            dst[((4 * 8 + ks) * 64 + kq * 16 + c) * 8 + j] = (_Float16)0.f;
    }
}

// ---------------- phi_q + out + denom + normalize; swapped QK, register butterfly ----------------
// grid (L/128, B*H) = (32,16), 2 row-tiles of 64. LDS: kvs 40K only (P frags from global/L2).
__global__ __launch_bounds__(256) void out_kernel7(const _Float16* __restrict__ q,
                                                   const _Float16* __restrict__ Phf,
                                                   const _Float16* __restrict__ kvtf,
                                                   _Float16* __restrict__ ao) {
    const int bh = blockIdx.y, b = bh >> 4, h = bh & 15;
    const int t = threadIdx.x, lane = t & 63, w = t >> 6;
    const int fr = lane & 15, kq = lane >> 4;

    __shared__ _Float16 kvs[2560 * 8];    // fragment-linear kvt  40KB

    {
        const _Float16* src = kvtf + (size_t)bh * 20480 + t * 8;
#pragma unroll
        for (int i = 0; i < 10; i++)
            gload16(src + i * 2048, kvs + t * 8 + i * 2048);
    }
    __syncthreads();

    const int srcA = fr + 16 * ((2 * kq) & 3);
    const int srcB = fr + 16 * ((2 * kq + 1) & 3);
    const bool hi  = (kq & 2) != 0;

    for (int rt = 0; rt < 2; ++rt) {
        const int l0 = blockIdx.x * 128 + rt * 64;

        const _Float16* qp = q + (size_t)(b * L + l0 + w * 16 + fr) * D + h * DK + kq * 8;
        f16x8 aq0 = *(const f16x8*)qp;
        f16x8 aq1 = *(const f16x8*)(qp + 32);
        float ns = 0.f;
#pragma unroll
        for (int j = 0; j < 8; j++)
            ns += (float)aq0[j] * (float)aq0[j] + (float)aq1[j] * (float)aq1[j];
        ns += __shfl_xor(ns, 16);
        ns += __shfl_xor(ns, 32);
        ns *= HALF_DN2;

        f32x4 pr[16];
#pragma unroll
        for (int nf = 0; nf < 16; nf++) {
            f16x8 a0 = *(const f16x8*)&Phf[((size_t)(nf * 2 + 0) * 64 + lane) * 8];
            f16x8 a1 = *(const f16x8*)&Phf[((size_t)(nf * 2 + 1) * 64 + lane) * 8];
            f32x4 c = {0.f, 0.f, 0.f, 0.f};
            c = __builtin_amdgcn_mfma_f32_16x16x32_f16(a0, aq0, c, 0, 0, 0);
            c = __builtin_amdgcn_mfma_f32_16x16x32_f16(a1, aq1, c, 0, 0, 0);
            pr[nf] = c;
        }
        float mx = -1e30f;
#pragma unroll
        for (int nf = 0; nf < 16; nf++)
#pragma unroll
            for (int r = 0; r < 4; r++) {
                pr[nf][r] *= DNORM;
                mx = fmaxf(mx, pr[nf][r]);
            }
        mx = fmaxf(mx, __shfl_xor(mx, 16));
        mx = fmaxf(mx, __shfl_xor(mx, 32));
        const float sub = mx + ns;

        unsigned pk_[16][2];
#pragma unroll
        for (int nf = 0; nf < 16; nf++) {
#pragma unroll
            for (int p = 0; p < 2; p++) {
                float v0 = RATIO * (__expf(pr[nf][2 * p]     - sub) + 1e-6f);
                float v1 = RATIO * (__expf(pr[nf][2 * p + 1] - sub) + 1e-6f);
                f16x2 pq = {(_Float16)v0, (_Float16)v1};
                pk_[nf][p] = __builtin_bit_cast(unsigned, pq);
            }
        }

        f32x4 acc[5];
#pragma unroll
        for (int n2 = 0; n2 < 5; n2++) acc[n2] = (f32x4){0.f, 0.f, 0.f, 0.f};
#pragma unroll
        for (int ks = 0; ks < 8; ks++) {
            unsigned u0 = __shfl(pk_[2 * ks][0], srcA);
            unsigned u1 = __shfl(pk_[2 * ks][1], srcA);
            unsigned u2 = __shfl(pk_[2 * ks][0], srcB);
            unsigned u3 = __shfl(pk_[2 * ks][1], srcB);
            unsigned v0 = __shfl(pk_[2 * ks + 1][0], srcA);
            unsigned v1 = __shfl(pk_[2 * ks + 1][1], srcA);
            unsigned v2 = __shfl(pk_[2 * ks + 1][0], srcB);
            unsigned v3 = __shfl(pk_[2 * ks + 1][1], srcB);
            u32x4 wv;
            wv[0] = hi ? v0 : u0;
            wv[1] = hi ? v1 : u1;
            wv[2] = hi ? v2 : u2;
            wv[3] = hi ? v3 : u3;
            f16x8 af = __builtin_bit_cast(f16x8, wv);
#pragma unroll
            for (int n2 = 0; n2 < 5; n2++) {
                f16x8 bf = *(const f16x8*)&kvs[((n2 * 8 + ks) * 64 + lane) * 8];
                acc[n2] = __builtin_amdgcn_mfma_f32_16x16x32_f16(af, bf, acc[n2], 0, 0, 0);
            }
        }
#pragma unroll
        for (int r = 0; r < 4; r++) {
            float den = __shfl(acc[4][r], (lane & 48));
            float inv = 1.f / fmaxf(den, 1e-6f);
            const int row = l0 + w * 16 + kq * 4 + r;
            _Float16* dst = ao + (size_t)(b * L + row) * D + h * DK;
#pragma unroll
            for (int n2 = 0; n2 < 4; n2++)
                dst[n2 * 16 + fr] = (_Float16)(acc[n2][r] * inv);
        }
    }
}

extern "C" void kernel_launch(void* const* d_in, const int* in_sizes, int n_in,
                              void* d_out, int out_size, void* d_ws, size_t ws_size,
                              hipStream_t stream) {
    (void)in_sizes; (void)n_in; (void)out_size; (void)ws_size;
    const float* X    = (const float*)d_in[0];
    const int*   mask = (const int*)d_in[1];
    const float* Wq   = (const float*)d_in[2];
    const float* Wk   = (const float*)d_in[3];
    const float* Wv   = (const float*)d_in[4];
    const float* Wo   = (const float*)d_in[5];
    const float* P    = (const float*)d_in[6];

    char* ws = (char*)d_ws;
    _Float16* Xh    = (_Float16*)ws;                      // 0..32M
    _Float16* kvb   = (_Float16*)(ws + 33554432);         // 32M..96M  [k|v] stride 2048
    _Float16* attn  = (_Float16*)(ws + 33554432);         // reuses dead k-half after kv_kernel
    _Float16* bufQ  = (_Float16*)(ws + 67108864);         // reuses dead v-half after kv_kernel
    float* kvpart   = (float*)(ws + 100663296);           // 32MB
    float* kspart   = (float*)(ws + 134217728);           // 512KB
    _Float16* kvt   = (_Float16*)(ws + 134742016);        // 2.62MB
    _Float16* Wall  = (_Float16*)(ws + 137363456);        // 8MB [Wk;Wv;Wq;Wo]
    _Float16* Phf   = (_Float16*)(ws + 145752064);        // 32KB
    float* out      = (float*)d_out;

    dim3 blk(256);
    hipLaunchKernelGGL(cast_f32_f16, dim3(8192), blk, 0, stream, X, Xh, 2097152);
    hipLaunchKernelGGL(cast_w4, dim3(512, 4), blk, 0, stream, Wk, Wv, Wq, Wo, Wall);
    hipLaunchKernelGGL(cast_P_frag, dim3(1), blk, 0, stream, P, Phf);

    // K+V fused projection: C[16384][2048] = Xh @ [Wk;Wv]^T
    hipLaunchKernelGGL((gemm_f16<_Float16>), dim3(16, 128), blk, 0, stream, Xh, Wall, kvb, 2048, D);

    hipLaunchKernelGGL(kv_kernel4, dim3(NCH, B * H), blk, 0, stream, kvb, mask, Phf, kvpart, kspart);
    hipLaunchKernelGGL(reduce_kvt2, dim3(4, 64), blk, 0, stream, kvpart, kspart, kvt);

    // Q projection (into dead v-half)
    hipLaunchKernelGGL((gemm_f16<_Float16>), dim3(8, 128), blk, 0, stream, Xh, Wall + 2 * 1048576, bufQ, D, D);

    hipLaunchKernelGGL(out_kernel7, dim3(L / 128, B * H), blk, 0, stream, bufQ, Phf, kvt, attn);

    hipLaunchKernelGGL((gemm_f16<float>), dim3(8, 128), blk, 0, stream, attn, Wall + 3 * 1048576, out, D, D);
}

// Round 12
// 330.635 us; speedup vs baseline: 1.3026x; 1.0148x over previous
//
#include <hip/hip_runtime.h>
#include <math.h>

#define B 4
#define L 4096
#define D 1024
#define H 16
#define DK 64
#define M 256
#define NTOK (B*L)        // 16384
#define NCH 8
#define LC (L/NCH)        // 512

// dn = 64^-0.25 = 2^-1.5 ; dn^2*0.5 = 0.0625 ; ratio = 256^-0.5 = 0.0625
#define DNORM 0.35355339059327373f
#define HALF_DN2 0.0625f
#define RATIO 0.0625f

typedef _Float16 f16x8 __attribute__((ext_vector_type(8)));
typedef _Float16 f16x2 __attribute__((ext_vector_type(2)));
typedef float f32x4 __attribute__((ext_vector_type(4)));
typedef unsigned u32x4 __attribute__((ext_vector_type(4)));

// XOR-swizzled LDS index for [col][64 l] fp16 tiles: 8-half blocks permuted by col&7
#define SWZ(col, l) ((col) * 64 + (((l) & 7) | ((((((l) >> 3)) ^ (col)) & 7) << 3)))

__device__ __forceinline__ void gload16(const void* g, void* l) {
    __builtin_amdgcn_global_load_lds((const __attribute__((address_space(1))) unsigned*)g,
                                     (__attribute__((address_space(3))) unsigned*)l, 16, 0, 0);
}

// ---------------- fp32 -> fp16 cast (8 elems/thread) ----------------
__global__ __launch_bounds__(256) void cast_f32_f16(const float* __restrict__ in,
                                                    _Float16* __restrict__ out, int n8) {
    int i = blockIdx.x * 256 + threadIdx.x;
    if (i >= n8) return;
    const float4* p = (const float4*)(in + (size_t)i * 8);
    float4 a = p[0], b = p[1];
    f16x8 o;
    o[0] = (_Float16)a.x; o[1] = (_Float16)a.y; o[2] = (_Float16)a.z; o[3] = (_Float16)a.w;
    o[4] = (_Float16)b.x; o[5] = (_Float16)b.y; o[6] = (_Float16)b.z; o[7] = (_Float16)b.w;
    *(f16x8*)(out + (size_t)i * 8) = o;
}

// ---------------- all four W casts in one launch: Wall = [Wk;Wv;Wq;Wo] fp16 ----------------
__global__ __launch_bounds__(256) void cast_w4(const float* __restrict__ Wk,
                                               const float* __restrict__ Wv,
                                               const float* __restrict__ Wq,
                                               const float* __restrict__ Wo,
                                               _Float16* __restrict__ Wall) {
    const int y = blockIdx.y;
    const float* src = (y == 0) ? Wk : (y == 1) ? Wv : (y == 2) ? Wq : Wo;
    const int i = blockIdx.x * 256 + threadIdx.x;
    const float4* p = (const float4*)(src + (size_t)i * 8);
    float4 a = p[0], b = p[1];
    f16x8 o;
    o[0] = (_Float16)a.x; o[1] = (_Float16)a.y; o[2] = (_Float16)a.z; o[3] = (_Float16)a.w;
    o[4] = (_Float16)b.x; o[5] = (_Float16)b.y; o[6] = (_Float16)b.z; o[7] = (_Float16)b.w;
    *(f16x8*)(Wall + (size_t)y * 1048576 + (size_t)i * 8) = o;
}

// ---------------- P fp32 [256][64] -> fp16 FRAGMENT-LINEAR image ----------------
// chunk c = (nf*2+kh)*64 + lane, lane=(kq*16+fr): holds P[nf*16+fr][kh*32+kq*8 + j], j=0..7
__global__ __launch_bounds__(256) void cast_P_frag(const float* __restrict__ P,
                                                   _Float16* __restrict__ Phf) {
    const int t = threadIdx.x;
#pragma unroll
    for (int i = 0; i < 8; i++) {
        const int c = t + i * 256;
        const int f = c >> 6, lane2 = c & 63;
        const int nf = f >> 1, kh = f & 1;
        const int fr = lane2 & 15, kq2 = lane2 >> 4;
        const float* src = P + (nf * 16 + fr) * 64 + kh * 32 + kq2 * 8;
        f16x8 o;
#pragma unroll
        for (int j = 0; j < 8; j++) o[j] = (_Float16)src[j];
        *(f16x8*)(Phf + (size_t)c * 8) = o;
    }
}

// ---------------- fp16 MFMA GEMM, BK=64, XOR-swizzled LDS, XCD-chunked block swizzle ----------------
// C[n][o] = sum_k A[n][k]*W[o][k]. LDS slot p of row r holds source chunk (p ^ (r&7)).
// T1: nwg must be divisible by 8 (all uses: 2048/1024). Each XCD gets contiguous work chunk.
template <typename CT>
__global__ __launch_bounds__(256) void gemm_f16(const _Float16* __restrict__ A,
                                                const _Float16* __restrict__ W,
                                                CT* __restrict__ C,
                                                int N, int K) {
    __shared__ _Float16 As[128 * 64];
    __shared__ _Float16 Bs[128 * 64];
    const int t    = threadIdx.x;
    const int lane = t & 63;
    const int w    = t >> 6;
    const int wr   = w >> 1, wc = w & 1;

    const int nwg = gridDim.x * gridDim.y;
    int lid = blockIdx.y * gridDim.x + blockIdx.x;
    lid = (lid & 7) * (nwg >> 3) + (lid >> 3);
    const int bx = lid % gridDim.x, by = lid / gridDim.x;
    const int brow = by * 128, bcol = bx * 128;

    const int fr = lane & 15;
    const int kq = lane >> 4;

    int srow[4], soff[4];
#pragma unroll
    for (int i = 0; i < 4; i++) {
        const int c = t + i * 256;
        srow[i] = c >> 3;
        soff[i] = ((c & 7) ^ ((c >> 3) & 7)) * 8;
    }

    f32x4 acc[4][4];
#pragma unroll
    for (int i = 0; i < 4; i++)
#pragma unroll
        for (int j = 0; j < 4; j++) acc[i][j] = (f32x4){0.f, 0.f, 0.f, 0.f};

    for (int k0 = 0; k0 < K; k0 += 64) {
        __syncthreads();
#pragma unroll
        for (int i = 0; i < 4; i++) {
            const int c = t + i * 256;
            gload16(A + (size_t)(brow + srow[i]) * K + k0 + soff[i], As + c * 8);
            gload16(W + (size_t)(bcol + srow[i]) * K + k0 + soff[i], Bs + c * 8);
        }
        __syncthreads();
#pragma unroll
        for (int kh = 0; kh < 2; kh++) {
            f16x8 af[4], bf[4];
#pragma unroll
            for (int mi = 0; mi < 4; mi++) {
                const int row = wr * 64 + mi * 16 + fr;
                af[mi] = *(const f16x8*)&As[row * 64 + (((kh * 4 + kq) ^ (row & 7)) << 3)];
            }
#pragma unroll
            for (int ni = 0; ni < 4; ni++) {
                const int row = wc * 64 + ni * 16 + fr;
                bf[ni] = *(const f16x8*)&Bs[row * 64 + (((kh * 4 + kq) ^ (row & 7)) << 3)];
            }
#pragma unroll
            for (int mi = 0; mi < 4; mi++)
#pragma unroll
                for (int ni = 0; ni < 4; ni++)
                    acc[mi][ni] = __builtin_amdgcn_mfma_f32_16x16x32_f16(af[mi], bf[ni], acc[mi][ni], 0, 0, 0);
        }
    }
#pragma unroll
    for (int mi = 0; mi < 4; mi++) {
#pragma unroll
        for (int ni = 0; ni < 4; ni++) {
            const int row = brow + wr * 64 + mi * 16 + kq * 4;
            const int col = bcol + wc * 64 + ni * 16 + fr;
#pragma unroll
            for (int r = 0; r < 4; r++)
                C[(size_t)(row + r) * N + col] = (CT)acc[mi][ni][r];
        }
    }
}

// ---------------- MFMA phi_k + kv/ksum partials; P frags from global (L2-resident) ----------------
// k/v interleaved in kvb: row stride 2048, k at +0, v at +1024. LDS 42KB.
__global__ __launch_bounds__(256) void kv_kernel4(const _Float16* __restrict__ kvb,
                                                  const int* __restrict__ mask,
                                                  const _Float16* __restrict__ Phf,
                                                  float* __restrict__ kvpart,
                                                  float* __restrict__ kspart) {
    const int bh = blockIdx.y, b = bh >> 4, h = bh & 15;
    const int ch = blockIdx.x;
    const int t = threadIdx.x, lane = t & 63, w = t >> 6;
    const int fr = lane & 15, kq = lane >> 4;

    __shared__ _Float16 phis[256 * 64];   // [m][l] swizzled          32KB
    __shared__ _Float16 vst[80 * 64];     // [d][l] swizzled; row64=1 10KB

    if (t < 128) {
        const int row = 64 + (t >> 3), off = (t & 7) * 8;
        const _Float16 val = (row == 64) ? (_Float16)1.0f : (_Float16)0.0f;
        f16x8 o = {val, val, val, val, val, val, val, val};
        *(f16x8*)&vst[row * 64 + off] = o;
    }
    __syncthreads();

    f32x4 acc[4][5];
#pragma unroll
    for (int mf = 0; mf < 4; mf++)
#pragma unroll
        for (int n2 = 0; n2 < 5; n2++) acc[mf][n2] = (f32x4){0.f, 0.f, 0.f, 0.f};

    const int rr = t & 31, seg = t >> 5;

    for (int tile = 0; tile < LC / 64; ++tile) {
        const int l0 = ch * LC + tile * 64;

        {
            const _Float16* v0 = kvb + (size_t)(b * L + l0 + 2 * rr) * 2048 + 1024 + h * DK + seg * 8;
            f16x8 a0 = *(const f16x8*)v0;
            f16x8 a1 = *(const f16x8*)(v0 + 2048);
#pragma unroll
            for (int j = 0; j < 8; j++) {
                const int d = seg * 8 + j;
                f16x2 pk = {a0[j], a1[j]};
                *(f16x2*)&vst[SWZ(d, 2 * rr)] = pk;
            }
        }

        const _Float16* krow = kvb + (size_t)(b * L + l0 + w * 16 + fr) * 2048 + h * DK + kq * 8;
        f16x8 ak0 = *(const f16x8*)krow;
        f16x8 ak1 = *(const f16x8*)(krow + 32);
        float ns = 0.f;
#pragma unroll
        for (int j = 0; j < 8; j++)
            ns += (float)ak0[j] * (float)ak0[j] + (float)ak1[j] * (float)ak1[j];
        ns += __shfl_xor(ns, 16);
        ns += __shfl_xor(ns, 32);
        ns *= HALF_DN2;

        f32x4 pr[16];
#pragma unroll
        for (int nf = 0; nf < 16; nf++) {
            f16x8 b0 = *(const f16x8*)&Phf[((size_t)(nf * 2 + 0) * 64 + lane) * 8];
            f16x8 b1 = *(const f16x8*)&Phf[((size_t)(nf * 2 + 1) * 64 + lane) * 8];
            f32x4 c = {0.f, 0.f, 0.f, 0.f};
            c = __builtin_amdgcn_mfma_f32_16x16x32_f16(ak0, b0, c, 0, 0, 0);
            c = __builtin_amdgcn_mfma_f32_16x16x32_f16(ak1, b1, c, 0, 0, 0);
            pr[nf] = c;
        }
        float mx[4] = {-1e30f, -1e30f, -1e30f, -1e30f};
#pragma unroll
        for (int nf = 0; nf < 16; nf++)
#pragma unroll
            for (int r = 0; r < 4; r++) {
                pr[nf][r] *= DNORM;
                mx[r] = fmaxf(mx[r], pr[nf][r]);
            }
#pragma unroll
        for (int r = 0; r < 4; r++) {
            mx[r] = fmaxf(mx[r], __shfl_xor(mx[r], 1));
            mx[r] = fmaxf(mx[r], __shfl_xor(mx[r], 2));
            mx[r] = fmaxf(mx[r], __shfl_xor(mx[r], 4));
            mx[r] = fmaxf(mx[r], __shfl_xor(mx[r], 8));
        }
        float sub[4], mkv[4];
#pragma unroll
        for (int r = 0; r < 4; r++) {
            sub[r] = mx[r] + __shfl(ns, kq * 4 + r);
            mkv[r] = (float)mask[b * L + l0 + w * 16 + kq * 4 + r];
        }
#pragma unroll
        for (int nf = 0; nf < 16; nf++) {
            const int col = nf * 16 + fr;
#pragma unroll
            for (int rp = 0; rp < 2; rp++) {
                const int row = w * 16 + kq * 4 + 2 * rp;
                float v0 = mkv[2 * rp]     * (RATIO * (__expf(pr[nf][2 * rp]     - sub[2 * rp])     + 1e-6f));
                float v1 = mkv[2 * rp + 1] * (RATIO * (__expf(pr[nf][2 * rp + 1] - sub[2 * rp + 1]) + 1e-6f));
                f16x2 pk = {(_Float16)v0, (_Float16)v1};
                *(f16x2*)&phis[SWZ(col, row)] = pk;
            }
        }
        __syncthreads();

        f16x8 bfr[5][2];
#pragma unroll
        for (int n2 = 0; n2 < 5; n2++)
#pragma unroll
            for (int ks = 0; ks < 2; ks++)
                bfr[n2][ks] = *(const f16x8*)&vst[SWZ(n2 * 16 + fr, ks * 32 + kq * 8)];
#pragma unroll
        for (int mf = 0; mf < 4; mf++) {
            const int m = w * 64 + mf * 16 + fr;
            f16x8 a0 = *(const f16x8*)&phis[SWZ(m, kq * 8)];
            f16x8 a1 = *(const f16x8*)&phis[SWZ(m, 32 + kq * 8)];
#pragma unroll
            for (int n2 = 0; n2 < 5; n2++) {
                acc[mf][n2] = __builtin_amdgcn_mfma_f32_16x16x32_f16(a0, bfr[n2][0], acc[mf][n2], 0, 0, 0);
                acc[mf][n2] = __builtin_amdgcn_mfma_f32_16x16x32_f16(a1, bfr[n2][1], acc[mf][n2], 0, 0, 0);
            }
        }
        __syncthreads();
    }

    float* kvp = kvpart + ((size_t)ch * 64 + bh) * M * DK;
    float* ksp = kspart + ((size_t)ch * 64 + bh) * M;
#pragma unroll
    for (int mf = 0; mf < 4; mf++) {
#pragma unroll
        for (int r = 0; r < 4; r++) {
            const int m = w * 64 + mf * 16 + kq * 4 + r;
#pragma unroll
            for (int n2 = 0; n2 < 4; n2++)
                kvp[(size_t)m * DK + n2 * 16 + fr] = acc[mf][n2][r];
            if (fr == 0) ksp[m] = acc[mf][4][r];
        }
    }
}

// ---------------- reduce partials -> kvt fp16 FRAGMENT-LINEAR ----------------
// grid (4, 64): block = (d-quarter, bh). kvt[bh][(n2*8+ks)*64 + kq*16+fr][8]; n2=4 -> ksum/zeros
__global__ __launch_bounds__(256) void reduce_kvt2(const float* __restrict__ kvp,
                                                   const float* __restrict__ ksp,
                                                   _Float16* __restrict__ kvt) {
    const int dq = blockIdx.x, bh = blockIdx.y;
    const int t  = threadIdx.x;   // m index
    float s[16];
#pragma unroll
    for (int c = 0; c < 16; c++) s[c] = 0.f;
    for (int ch = 0; ch < NCH; ch++) {
        const float* src = kvp + (((size_t)ch * 64 + bh) * M + t) * DK + dq * 16;
#pragma unroll
        for (int c4 = 0; c4 < 4; c4++) {
            float4 v = *(const float4*)(src + c4 * 4);
            s[c4 * 4 + 0] += v.x; s[c4 * 4 + 1] += v.y;
            s[c4 * 4 + 2] += v.z; s[c4 * 4 + 3] += v.w;
        }
    }
    _Float16* dst = kvt + (size_t)bh * 20480;
    const int ks = t >> 5, kq = (t >> 3) & 3, j = t & 7;
#pragma unroll
    for (int c = 0; c < 16; c++)
        dst[((dq * 8 + ks) * 64 + kq * 16 + c) * 8 + j] = (_Float16)s[c];
    if (dq == 0) {
        float s64 = 0.f;
        for (int ch = 0; ch < NCH; ch++) s64 += ksp[((size_t)ch * 64 + bh) * M + t];
        dst[((4 * 8 + ks) * 64 + kq * 16 + 0) * 8 + j] = (_Float16)s64;
#pragma unroll
        for (int c = 1; c < 16; c++)
            dst[((4 * 8 + ks) * 64 + kq * 16 + c) * 8 + j] = (_Float16)0.f;
    }
}

// ---------------- phi_q + out + denom + normalize; swapped QK, register butterfly ----------------
// grid (L/64, B*H) = (64,64) = 4096 blocks, ONE 64-row tile per block.
// XCD swizzle (bijective, nwg%8==0) clusters same-bh blocks on one XCD.
// LDS: kvs 40K only (P frags from global/L2).
__global__ __launch_bounds__(256) void out_kernel8(const _Float16* __restrict__ q,
                                                   const _Float16* __restrict__ Phf,
                                                   const _Float16* __restrict__ kvtf,
                                                   _Float16* __restrict__ ao) {
    const int nwg = gridDim.x * gridDim.y;               // 4096
    int lid = blockIdx.y * gridDim.x + blockIdx.x;
    lid = (lid & 7) * (nwg >> 3) + (lid >> 3);           // bijective XCD chunking
    const int bh = lid >> 6, lblk = lid & 63;
    const int b = bh >> 4, h = bh & 15;
    const int l0 = lblk * 64;
    const int t = threadIdx.x, lane = t & 63, w = t >> 6;
    const int fr = lane & 15, kq = lane >> 4;

    __shared__ _Float16 kvs[2560 * 8];    // fragment-linear kvt  40KB

    {
        const _Float16* src = kvtf + (size_t)bh * 20480 + t * 8;
#pragma unroll
        for (int i = 0; i < 10; i++)
            gload16(src + i * 2048, kvs + t * 8 + i * 2048);
    }

    const int srcA = fr + 16 * ((2 * kq) & 3);
    const int srcB = fr + 16 * ((2 * kq + 1) & 3);
    const bool hi  = (kq & 2) != 0;

    // ---- q fragment (B operand) direct from global + row norm ----
    const _Float16* qp = q + (size_t)(b * L + l0 + w * 16 + fr) * D + h * DK + kq * 8;
    f16x8 aq0 = *(const f16x8*)qp;
    f16x8 aq1 = *(const f16x8*)(qp + 32);
    float ns = 0.f;
#pragma unroll
    for (int j = 0; j < 8; j++)
        ns += (float)aq0[j] * (float)aq0[j] + (float)aq1[j] * (float)aq1[j];
    ns += __shfl_xor(ns, 16);
    ns += __shfl_xor(ns, 32);
    ns *= HALF_DN2;

    // ---- phase 1 (swapped): pr[nf] = P(nf-tile) x q -> C[m][l], col l = fr ----
    f32x4 pr[16];
#pragma unroll
    for (int nf = 0; nf < 16; nf++) {
        f16x8 a0 = *(const f16x8*)&Phf[((size_t)(nf * 2 + 0) * 64 + lane) * 8];
        f16x8 a1 = *(const f16x8*)&Phf[((size_t)(nf * 2 + 1) * 64 + lane) * 8];
        f32x4 c = {0.f, 0.f, 0.f, 0.f};
        c = __builtin_amdgcn_mfma_f32_16x16x32_f16(a0, aq0, c, 0, 0, 0);
        c = __builtin_amdgcn_mfma_f32_16x16x32_f16(a1, aq1, c, 0, 0, 0);
        pr[nf] = c;
    }
    float mx = -1e30f;
#pragma unroll
    for (int nf = 0; nf < 16; nf++)
#pragma unroll
        for (int r = 0; r < 4; r++) {
            pr[nf][r] *= DNORM;
            mx = fmaxf(mx, pr[nf][r]);
        }
    mx = fmaxf(mx, __shfl_xor(mx, 16));
    mx = fmaxf(mx, __shfl_xor(mx, 32));
    const float sub = mx + ns;

    // ---- phi + pack to f16x2 (in-register) ----
    unsigned pk_[16][2];
#pragma unroll
    for (int nf = 0; nf < 16; nf++) {
#pragma unroll
        for (int p = 0; p < 2; p++) {
            float v0 = RATIO * (__expf(pr[nf][2 * p]     - sub) + 1e-6f);
            float v1 = RATIO * (__expf(pr[nf][2 * p + 1] - sub) + 1e-6f);
            f16x2 pq = {(_Float16)v0, (_Float16)v1};
            pk_[nf][p] = __builtin_bit_cast(unsigned, pq);
        }
    }
    __syncthreads();   // kvs staged (drains vmcnt; hidden under phase 1)

    // ---- phase 2: out[l][d] = phi @ kv^T ; A-frags via butterfly shuffles ----
    f32x4 acc[5];
#pragma unroll
    for (int n2 = 0; n2 < 5; n2++) acc[n2] = (f32x4){0.f, 0.f, 0.f, 0.f};
#pragma unroll
    for (int ks = 0; ks < 8; ks++) {
        unsigned u0 = __shfl(pk_[2 * ks][0], srcA);
        unsigned u1 = __shfl(pk_[2 * ks][1], srcA);
        unsigned u2 = __shfl(pk_[2 * ks][0], srcB);
        unsigned u3 = __shfl(pk_[2 * ks][1], srcB);
        unsigned v0 = __shfl(pk_[2 * ks + 1][0], srcA);
        unsigned v1 = __shfl(pk_[2 * ks + 1][1], srcA);
        unsigned v2 = __shfl(pk_[2 * ks + 1][0], srcB);
        unsigned v3 = __shfl(pk_[2 * ks + 1][1], srcB);
        u32x4 wv;
        wv[0] = hi ? v0 : u0;
        wv[1] = hi ? v1 : u1;
        wv[2] = hi ? v2 : u2;
        wv[3] = hi ? v3 : u3;
        f16x8 af = __builtin_bit_cast(f16x8, wv);
#pragma unroll
        for (int n2 = 0; n2 < 5; n2++) {
            f16x8 bf = *(const f16x8*)&kvs[((n2 * 8 + ks) * 64 + lane) * 8];
            acc[n2] = __builtin_amdgcn_mfma_f32_16x16x32_f16(af, bf, acc[n2], 0, 0, 0);
        }
    }
#pragma unroll
    for (int r = 0; r < 4; r++) {
        float den = __shfl(acc[4][r], (lane & 48));
        float inv = 1.f / fmaxf(den, 1e-6f);
        const int row = l0 + w * 16 + kq * 4 + r;
        _Float16* dst = ao + (size_t)(b * L + row) * D + h * DK;
#pragma unroll
        for (int n2 = 0; n2 < 4; n2++)
            dst[n2 * 16 + fr] = (_Float16)(acc[n2][r] * inv);
    }
}

extern "C" void kernel_launch(void* const* d_in, const int* in_sizes, int n_in,
                              void* d_out, int out_size, void* d_ws, size_t ws_size,
                              hipStream_t stream) {
    (void)in_sizes; (void)n_in; (void)out_size; (void)ws_size;
    const float* X    = (const float*)d_in[0];
    const int*   mask = (const int*)d_in[1];
    const float* Wq   = (const float*)d_in[2];
    const float* Wk   = (const float*)d_in[3];
    const float* Wv   = (const float*)d_in[4];
    const float* Wo   = (const float*)d_in[5];
    const float* P    = (const float*)d_in[6];

    char* ws = (char*)d_ws;
    _Float16* Xh    = (_Float16*)ws;                      // 0..32M
    _Float16* kvb   = (_Float16*)(ws + 33554432);         // 32M..96M  [k|v] stride 2048
    _Float16* attn  = (_Float16*)(ws + 33554432);         // reuses dead kvb space after kv_kernel
    _Float16* bufQ  = (_Float16*)(ws + 67108864);         // reuses dead kvb space after kv_kernel
    float* kvpart   = (float*)(ws + 100663296);           // 32MB
    float* kspart   = (float*)(ws + 134217728);           // 512KB
    _Float16* kvt   = (_Float16*)(ws + 134742016);        // 2.62MB
    _Float16* Wall  = (_Float16*)(ws + 137363456);        // 8MB [Wk;Wv;Wq;Wo]
    _Float16* Phf   = (_Float16*)(ws + 145752064);        // 32KB
    float* out      = (float*)d_out;

    dim3 blk(256);
    hipLaunchKernelGGL(cast_f32_f16, dim3(8192), blk, 0, stream, X, Xh, 2097152);
    hipLaunchKernelGGL(cast_w4, dim3(512, 4), blk, 0, stream, Wk, Wv, Wq, Wo, Wall);
    hipLaunchKernelGGL(cast_P_frag, dim3(1), blk, 0, stream, P, Phf);

    // K+V fused projection: C[16384][2048] = Xh @ [Wk;Wv]^T
    hipLaunchKernelGGL((gemm_f16<_Float16>), dim3(16, 128), blk, 0, stream, Xh, Wall, kvb, 2048, D);

    hipLaunchKernelGGL(kv_kernel4, dim3(NCH, B * H), blk, 0, stream, kvb, mask, Phf, kvpart, kspart);
    hipLaunchKernelGGL(reduce_kvt2, dim3(4, 64), blk, 0, stream, kvpart, kspart, kvt);

    // Q projection (into dead kvb space)
    hipLaunchKernelGGL((gemm_f16<_Float16>), dim3(8, 128), blk, 0, stream, Xh, Wall + 2 * 1048576, bufQ, D, D);

    hipLaunchKernelGGL(out_kernel8, dim3(L / 64, B * H), blk, 0, stream, bufQ, Phf, kvt, attn);

    hipLaunchKernelGGL((gemm_f16<float>), dim3(8, 128), blk, 0, stream, attn, Wall + 3 * 1048576, out, D, D);
}

// Round 13
// 298.958 us; speedup vs baseline: 1.4406x; 1.1060x over previous
//
#include <hip/hip_runtime.h>
#include <math.h>

#define B 4
#define L 4096
#define D 1024
#define H 16
#define DK 64
#define M 256
#define NTOK (B*L)        // 16384
#define NCH 8
#define LC (L/NCH)        // 512

// dn = 64^-0.25 = 2^-1.5 ; dn^2*0.5 = 0.0625 ; ratio = 256^-0.5 = 0.0625
#define DNORM 0.35355339059327373f
#define HALF_DN2 0.0625f
#define RATIO 0.0625f

typedef _Float16 f16x8 __attribute__((ext_vector_type(8)));
typedef _Float16 f16x2 __attribute__((ext_vector_type(2)));
typedef float f32x4 __attribute__((ext_vector_type(4)));
typedef unsigned u32x4 __attribute__((ext_vector_type(4)));

// XOR-swizzled LDS index for [col][64 l] fp16 tiles: 8-half blocks permuted by col&7
#define SWZ(col, l) ((col) * 64 + (((l) & 7) | ((((((l) >> 3)) ^ (col)) & 7) << 3)))

__device__ __forceinline__ void gload16(const void* g, void* l) {
    __builtin_amdgcn_global_load_lds((const __attribute__((address_space(1))) unsigned*)g,
                                     (__attribute__((address_space(3))) unsigned*)l, 16, 0, 0);
}

// ---------------- fp32 -> fp16 cast (8 elems/thread) ----------------
__global__ __launch_bounds__(256) void cast_f32_f16(const float* __restrict__ in,
                                                    _Float16* __restrict__ out, int n8) {
    int i = blockIdx.x * 256 + threadIdx.x;
    if (i >= n8) return;
    const float4* p = (const float4*)(in + (size_t)i * 8);
    float4 a = p[0], b = p[1];
    f16x8 o;
    o[0] = (_Float16)a.x; o[1] = (_Float16)a.y; o[2] = (_Float16)a.z; o[3] = (_Float16)a.w;
    o[4] = (_Float16)b.x; o[5] = (_Float16)b.y; o[6] = (_Float16)b.z; o[7] = (_Float16)b.w;
    *(f16x8*)(out + (size_t)i * 8) = o;
}

// ---------------- all four W casts in one launch: Wall = [Wk;Wv;Wq;Wo] fp16 ----------------
__global__ __launch_bounds__(256) void cast_w4(const float* __restrict__ Wk,
                                               const float* __restrict__ Wv,
                                               const float* __restrict__ Wq,
                                               const float* __restrict__ Wo,
                                               _Float16* __restrict__ Wall) {
    const int y = blockIdx.y;
    const float* src = (y == 0) ? Wk : (y == 1) ? Wv : (y == 2) ? Wq : Wo;
    const int i = blockIdx.x * 256 + threadIdx.x;
    const float4* p = (const float4*)(src + (size_t)i * 8);
    float4 a = p[0], b = p[1];
    f16x8 o;
    o[0] = (_Float16)a.x; o[1] = (_Float16)a.y; o[2] = (_Float16)a.z; o[3] = (_Float16)a.w;
    o[4] = (_Float16)b.x; o[5] = (_Float16)b.y; o[6] = (_Float16)b.z; o[7] = (_Float16)b.w;
    *(f16x8*)(Wall + (size_t)y * 1048576 + (size_t)i * 8) = o;
}

// ---------------- P fp32 [256][64] -> fp16 FRAGMENT-LINEAR image ----------------
__global__ __launch_bounds__(256) void cast_P_frag(const float* __restrict__ P,
                                                   _Float16* __restrict__ Phf) {
    const int t = threadIdx.x;
#pragma unroll
    for (int i = 0; i < 8; i++) {
        const int c = t + i * 256;
        const int f = c >> 6, lane2 = c & 63;
        const int nf = f >> 1, kh = f & 1;
        const int fr = lane2 & 15, kq2 = lane2 >> 4;
        const float* src = P + (nf * 16 + fr) * 64 + kh * 32 + kq2 * 8;
        f16x8 o;
#pragma unroll
        for (int j = 0; j < 8; j++) o[j] = (_Float16)src[j];
        *(f16x8*)(Phf + (size_t)c * 8) = o;
    }
}

// ---------------- 256x256 phase-interleaved counted-vmcnt fp16 MFMA GEMM ----------------
// C[n][o] = sum_k A[n][k] * W[o][k].  512 threads = 8 waves (2Mx4N), BK=64,
// double-buffered LDS (128KB), chunk-XOR swizzle (slot p of row r holds chunk p^(r&7)),
// 4 phases/K-tile, raw barriers + counted vmcnt(2) (never 0 in loop), setprio on MFMA.
template <typename CT>
__global__ __launch_bounds__(512) void gemm256(const _Float16* __restrict__ A,
                                               const _Float16* __restrict__ W,
                                               CT* __restrict__ C,
                                               int N, int K) {
    __shared__ _Float16 As[2][256 * 64];
    __shared__ _Float16 Bs[2][256 * 64];
    const int t = threadIdx.x;
    const int lane = t & 63;
    const int wid = t >> 6;
    const int wr = wid >> 2, wc = wid & 3;
    const int fr = lane & 15, kq = lane >> 4;

    const int nwg = gridDim.x * gridDim.y;
    int lid = blockIdx.y * gridDim.x + blockIdx.x;
    lid = (lid & 7) * (nwg >> 3) + (lid >> 3);      // bijective XCD chunking (nwg%8==0)
    const int bx = lid % gridDim.x, by = lid / gridDim.x;
    const int brow = by * 256, bcol = bx * 256;

    const int nt = K >> 6;

    f32x4 acc[8][4];
#pragma unroll
    for (int i = 0; i < 8; i++)
#pragma unroll
        for (int j = 0; j < 4; j++) acc[i][j] = (f32x4){0.f, 0.f, 0.f, 0.f};

    f16x8 af[4][2], bf[4][2];

#define STAGE_PAIR(buf_, k0_, j_) { \
    const int c_ = (j_) * 512 + t; \
    const int srow_ = c_ >> 3; \
    const int src_ = (c_ & 7) ^ (srow_ & 7); \
    gload16(A + (size_t)(brow + srow_) * K + (k0_) + src_ * 8, &As[buf_][c_ * 8]); \
    gload16(W + (size_t)(bcol + srow_) * K + (k0_) + src_ * 8, &Bs[buf_][c_ * 8]); }

#define READ_A(buf_, mh_) { \
    _Pragma("unroll") \
    for (int mi = 0; mi < 4; mi++) { \
        const int row_ = wr * 128 + (mh_) * 64 + mi * 16 + fr; \
        af[mi][0] = *(const f16x8*)&As[buf_][row_ * 64 + ((kq ^ (row_ & 7)) << 3)]; \
        af[mi][1] = *(const f16x8*)&As[buf_][row_ * 64 + (((4 + kq) ^ (row_ & 7)) << 3)]; \
    } }

#define READ_B2(buf_, nh_) { \
    _Pragma("unroll") \
    for (int ni = 0; ni < 2; ni++) { \
        const int row_ = wc * 64 + ((nh_) * 2 + ni) * 16 + fr; \
        bf[(nh_) * 2 + ni][0] = *(const f16x8*)&Bs[buf_][row_ * 64 + ((kq ^ (row_ & 7)) << 3)]; \
        bf[(nh_) * 2 + ni][1] = *(const f16x8*)&Bs[buf_][row_ * 64 + (((4 + kq) ^ (row_ & 7)) << 3)]; \
    } }

#define MFMA_Q(mh_, nh_) { \
    _Pragma("unroll") \
    for (int mi = 0; mi < 4; mi++) \
        _Pragma("unroll") \
        for (int ni = 0; ni < 2; ni++) { \
            acc[(mh_) * 4 + mi][(nh_) * 2 + ni] = __builtin_amdgcn_mfma_f32_16x16x32_f16( \
                af[mi][0], bf[(nh_) * 2 + ni][0], acc[(mh_) * 4 + mi][(nh_) * 2 + ni], 0, 0, 0); \
            acc[(mh_) * 4 + mi][(nh_) * 2 + ni] = __builtin_amdgcn_mfma_f32_16x16x32_f16( \
                af[mi][1], bf[(nh_) * 2 + ni][1], acc[(mh_) * 4 + mi][(nh_) * 2 + ni], 0, 0, 0); \
        } }

#define WAIT_LGKM { asm volatile("s_waitcnt lgkmcnt(0)" ::: "memory"); __builtin_amdgcn_sched_barrier(0); }
#define WAIT_VM2  { asm volatile("s_waitcnt vmcnt(2)" ::: "memory"); __builtin_amdgcn_sched_barrier(0); }
#define BAR __builtin_amdgcn_s_barrier()

    // prologue: tile0 pairs 0-3, tile1 pair0; validate buf0 keeping 2 in flight
    STAGE_PAIR(0, 0, 0);
    STAGE_PAIR(0, 0, 1);
    STAGE_PAIR(0, 0, 2);
    STAGE_PAIR(0, 0, 3);
    STAGE_PAIR(1, (nt > 1 ? 64 : 0), 0);
    WAIT_VM2; BAR;

    for (int tau = 0; tau < nt; ++tau) {
        const int cur = tau & 1, nxt = cur ^ 1;
        const int k1 = (tau + 1 < nt) ? (tau + 1) * 64 : 0;   // clamp: garbage into unread buf
        const int k2 = (tau + 2 < nt) ? (tau + 2) * 64 : 0;
        // P1
        READ_A(cur, 0);
        READ_B2(cur, 0);
        STAGE_PAIR(nxt, k1, 1);
        BAR; WAIT_LGKM;
        __builtin_amdgcn_s_setprio(1); MFMA_Q(0, 0); __builtin_amdgcn_s_setprio(0);
        BAR;
        // P2
        READ_B2(cur, 1);
        STAGE_PAIR(nxt, k1, 2);
        BAR; WAIT_LGKM;
        __builtin_amdgcn_s_setprio(1); MFMA_Q(0, 1); __builtin_amdgcn_s_setprio(0);
        BAR;
        // P3
        READ_A(cur, 1);
        STAGE_PAIR(nxt, k1, 3);
        BAR; WAIT_LGKM;
        __builtin_amdgcn_s_setprio(1); MFMA_Q(1, 0); __builtin_amdgcn_s_setprio(0);
        BAR;
        // P4 (no new reads; all frags live)
        __builtin_amdgcn_s_setprio(1); MFMA_Q(1, 1); __builtin_amdgcn_s_setprio(0);
        STAGE_PAIR(cur, k2, 0);   // tau+2 pair0; safe: all tau reads retired at P3 post-barrier
        WAIT_VM2; BAR;            // validates buf[nxt] for tau+1
    }
    asm volatile("s_waitcnt vmcnt(0)" ::: "memory");

    // epilogue: C layout col=lane&15, row=(lane>>4)*4+reg
#pragma unroll
    for (int mi = 0; mi < 8; mi++)
#pragma unroll
        for (int ni = 0; ni < 4; ni++) {
            const int row = brow + wr * 128 + mi * 16 + kq * 4;
            const int col = bcol + wc * 64 + ni * 16 + fr;
#pragma unroll
            for (int r = 0; r < 4; r++)
                C[(size_t)(row + r) * N + col] = (CT)acc[mi][ni][r];
        }
#undef STAGE_PAIR
#undef READ_A
#undef READ_B2
#undef MFMA_Q
#undef WAIT_LGKM
#undef WAIT_VM2
#undef BAR
}

// ---------------- MFMA phi_k + kv/ksum partials; P frags from global (L2-resident) ----------------
// k/v interleaved in kvb: row stride 2048, k at +0, v at +1024. LDS 42KB.
__global__ __launch_bounds__(256) void kv_kernel4(const _Float16* __restrict__ kvb,
                                                  const int* __restrict__ mask,
                                                  const _Float16* __restrict__ Phf,
                                                  float* __restrict__ kvpart,
                                                  float* __restrict__ kspart) {
    const int bh = blockIdx.y, b = bh >> 4, h = bh & 15;
    const int ch = blockIdx.x;
    const int t = threadIdx.x, lane = t & 63, w = t >> 6;
    const int fr = lane & 15, kq = lane >> 4;

    __shared__ _Float16 phis[256 * 64];   // [m][l] swizzled          32KB
    __shared__ _Float16 vst[80 * 64];     // [d][l] swizzled; row64=1 10KB

    if (t < 128) {
        const int row = 64 + (t >> 3), off = (t & 7) * 8;
        const _Float16 val = (row == 64) ? (_Float16)1.0f : (_Float16)0.0f;
        f16x8 o = {val, val, val, val, val, val, val, val};
        *(f16x8*)&vst[row * 64 + off] = o;
    }
    __syncthreads();

    f32x4 acc[4][5];
#pragma unroll
    for (int mf = 0; mf < 4; mf++)
#pragma unroll
        for (int n2 = 0; n2 < 5; n2++) acc[mf][n2] = (f32x4){0.f, 0.f, 0.f, 0.f};

    const int rr = t & 31, seg = t >> 5;

    for (int tile = 0; tile < LC / 64; ++tile) {
        const int l0 = ch * LC + tile * 64;

        {
            const _Float16* v0 = kvb + (size_t)(b * L + l0 + 2 * rr) * 2048 + 1024 + h * DK + seg * 8;
            f16x8 a0 = *(const f16x8*)v0;
            f16x8 a1 = *(const f16x8*)(v0 + 2048);
#pragma unroll
            for (int j = 0; j < 8; j++) {
                const int d = seg * 8 + j;
                f16x2 pk = {a0[j], a1[j]};
                *(f16x2*)&vst[SWZ(d, 2 * rr)] = pk;
            }
        }

        const _Float16* krow = kvb + (size_t)(b * L + l0 + w * 16 + fr) * 2048 + h * DK + kq * 8;
        f16x8 ak0 = *(const f16x8*)krow;
        f16x8 ak1 = *(const f16x8*)(krow + 32);
        float ns = 0.f;
#pragma unroll
        for (int j = 0; j < 8; j++)
            ns += (float)ak0[j] * (float)ak0[j] + (float)ak1[j] * (float)ak1[j];
        ns += __shfl_xor(ns, 16);
        ns += __shfl_xor(ns, 32);
        ns *= HALF_DN2;

        f32x4 pr[16];
#pragma unroll
        for (int nf = 0; nf < 16; nf++) {
            f16x8 b0 = *(const f16x8*)&Phf[((size_t)(nf * 2 + 0) * 64 + lane) * 8];
            f16x8 b1 = *(const f16x8*)&Phf[((size_t)(nf * 2 + 1) * 64 + lane) * 8];
            f32x4 c = {0.f, 0.f, 0.f, 0.f};
            c = __builtin_amdgcn_mfma_f32_16x16x32_f16(ak0, b0, c, 0, 0, 0);
            c = __builtin_amdgcn_mfma_f32_16x16x32_f16(ak1, b1, c, 0, 0, 0);
            pr[nf] = c;
        }
        float mx[4] = {-1e30f, -1e30f, -1e30f, -1e30f};
#pragma unroll
        for (int nf = 0; nf < 16; nf++)
#pragma unroll
            for (int r = 0; r < 4; r++) {
                pr[nf][r] *= DNORM;
                mx[r] = fmaxf(mx[r], pr[nf][r]);
            }
#pragma unroll
        for (int r = 0; r < 4; r++) {
            mx[r] = fmaxf(mx[r], __shfl_xor(mx[r], 1));
            mx[r] = fmaxf(mx[r], __shfl_xor(mx[r], 2));
            mx[r] = fmaxf(mx[r], __shfl_xor(mx[r], 4));
            mx[r] = fmaxf(mx[r], __shfl_xor(mx[r], 8));
        }
        float sub[4], mkv[4];
#pragma unroll
        for (int r = 0; r < 4; r++) {
            sub[r] = mx[r] + __shfl(ns, kq * 4 + r);
            mkv[r] = (float)mask[b * L + l0 + w * 16 + kq * 4 + r];
        }
#pragma unroll
        for (int nf = 0; nf < 16; nf++) {
            const int col = nf * 16 + fr;
#pragma unroll
            for (int rp = 0; rp < 2; rp++) {
                const int row = w * 16 + kq * 4 + 2 * rp;
                float v0 = mkv[2 * rp]     * (RATIO * (__expf(pr[nf][2 * rp]     - sub[2 * rp])     + 1e-6f));
                float v1 = mkv[2 * rp + 1] * (RATIO * (__expf(pr[nf][2 * rp + 1] - sub[2 * rp + 1]) + 1e-6f));
                f16x2 pk = {(_Float16)v0, (_Float16)v1};
                *(f16x2*)&phis[SWZ(col, row)] = pk;
            }
        }
        __syncthreads();

        f16x8 bfr[5][2];
#pragma unroll
        for (int n2 = 0; n2 < 5; n2++)
#pragma unroll
            for (int ks = 0; ks < 2; ks++)
                bfr[n2][ks] = *(const f16x8*)&vst[SWZ(n2 * 16 + fr, ks * 32 + kq * 8)];
#pragma unroll
        for (int mf = 0; mf < 4; mf++) {
            const int m = w * 64 + mf * 16 + fr;
            f16x8 a0 = *(const f16x8*)&phis[SWZ(m, kq * 8)];
            f16x8 a1 = *(const f16x8*)&phis[SWZ(m, 32 + kq * 8)];
#pragma unroll
            for (int n2 = 0; n2 < 5; n2++) {
                acc[mf][n2] = __builtin_amdgcn_mfma_f32_16x16x32_f16(a0, bfr[n2][0], acc[mf][n2], 0, 0, 0);
                acc[mf][n2] = __builtin_amdgcn_mfma_f32_16x16x32_f16(a1, bfr[n2][1], acc[mf][n2], 0, 0, 0);
            }
        }
        __syncthreads();
    }

    float* kvp = kvpart + ((size_t)ch * 64 + bh) * M * DK;
    float* ksp = kspart + ((size_t)ch * 64 + bh) * M;
#pragma unroll
    for (int mf = 0; mf < 4; mf++) {
#pragma unroll
        for (int r = 0; r < 4; r++) {
            const int m = w * 64 + mf * 16 + kq * 4 + r;
#pragma unroll
            for (int n2 = 0; n2 < 4; n2++)
                kvp[(size_t)m * DK + n2 * 16 + fr] = acc[mf][n2][r];
            if (fr == 0) ksp[m] = acc[mf][4][r];
        }
    }
}

// ---------------- reduce partials -> kvt fp16 FRAGMENT-LINEAR ----------------
__global__ __launch_bounds__(256) void reduce_kvt2(const float* __restrict__ kvp,
                                                   const float* __restrict__ ksp,
                                                   _Float16* __restrict__ kvt) {
    const int dq = blockIdx.x, bh = blockIdx.y;
    const int t  = threadIdx.x;   // m index
    float s[16];
#pragma unroll
    for (int c = 0; c < 16; c++) s[c] = 0.f;
    for (int ch = 0; ch < NCH; ch++) {
        const float* src = kvp + (((size_t)ch * 64 + bh) * M + t) * DK + dq * 16;
#pragma unroll
        for (int c4 = 0; c4 < 4; c4++) {
            float4 v = *(const float4*)(src + c4 * 4);
            s[c4 * 4 + 0] += v.x; s[c4 * 4 + 1] += v.y;
            s[c4 * 4 + 2] += v.z; s[c4 * 4 + 3] += v.w;
        }
    }
    _Float16* dst = kvt + (size_t)bh * 20480;
    const int ks = t >> 5, kq = (t >> 3) & 3, j = t & 7;
#pragma unroll
    for (int c = 0; c < 16; c++)
        dst[((dq * 8 + ks) * 64 + kq * 16 + c) * 8 + j] = (_Float16)s[c];
    if (dq == 0) {
        float s64 = 0.f;
        for (int ch = 0; ch < NCH; ch++) s64 += ksp[((size_t)ch * 64 + bh) * M + t];
        dst[((4 * 8 + ks) * 64 + kq * 16 + 0) * 8 + j] = (_Float16)s64;
#pragma unroll
        for (int c = 1; c < 16; c++)
            dst[((4 * 8 + ks) * 64 + kq * 16 + c) * 8 + j] = (_Float16)0.f;
    }
}

// ---------------- phi_q + out + denom + normalize; swapped QK, register butterfly ----------------
__global__ __launch_bounds__(256) void out_kernel8(const _Float16* __restrict__ q,
                                                   const _Float16* __restrict__ Phf,
                                                   const _Float16* __restrict__ kvtf,
                                                   _Float16* __restrict__ ao) {
    const int nwg = gridDim.x * gridDim.y;               // 4096
    int lid = blockIdx.y * gridDim.x + blockIdx.x;
    lid = (lid & 7) * (nwg >> 3) + (lid >> 3);           // bijective XCD chunking
    const int bh = lid >> 6, lblk = lid & 63;
    const int b = bh >> 4, h = bh & 15;
    const int l0 = lblk * 64;
    const int t = threadIdx.x, lane = t & 63, w = t >> 6;
    const int fr = lane & 15, kq = lane >> 4;

    __shared__ _Float16 kvs[2560 * 8];    // fragment-linear kvt  40KB

    {
        const _Float16* src = kvtf + (size_t)bh * 20480 + t * 8;
#pragma unroll
        for (int i = 0; i < 10; i++)
            gload16(src + i * 2048, kvs + t * 8 + i * 2048);
    }

    const int srcA = fr + 16 * ((2 * kq) & 3);
    const int srcB = fr + 16 * ((2 * kq + 1) & 3);
    const bool hi  = (kq & 2) != 0;

    const _Float16* qp = q + (size_t)(b * L + l0 + w * 16 + fr) * D + h * DK + kq * 8;
    f16x8 aq0 = *(const f16x8*)qp;
    f16x8 aq1 = *(const f16x8*)(qp + 32);
    float ns = 0.f;
#pragma unroll
    for (int j = 0; j < 8; j++)
        ns += (float)aq0[j] * (float)aq0[j] + (float)aq1[j] * (float)aq1[j];
    ns += __shfl_xor(ns, 16);
    ns += __shfl_xor(ns, 32);
    ns *= HALF_DN2;

    f32x4 pr[16];
#pragma unroll
    for (int nf = 0; nf < 16; nf++) {
        f16x8 a0 = *(const f16x8*)&Phf[((size_t)(nf * 2 + 0) * 64 + lane) * 8];
        f16x8 a1 = *(const f16x8*)&Phf[((size_t)(nf * 2 + 1) * 64 + lane) * 8];
        f32x4 c = {0.f, 0.f, 0.f, 0.f};
        c = __builtin_amdgcn_mfma_f32_16x16x32_f16(a0, aq0, c, 0, 0, 0);
        c = __builtin_amdgcn_mfma_f32_16x16x32_f16(a1, aq1, c, 0, 0, 0);
        pr[nf] = c;
    }
    float mx = -1e30f;
#pragma unroll
    for (int nf = 0; nf < 16; nf++)
#pragma unroll
        for (int r = 0; r < 4; r++) {
            pr[nf][r] *= DNORM;
            mx = fmaxf(mx, pr[nf][r]);
        }
    mx = fmaxf(mx, __shfl_xor(mx, 16));
    mx = fmaxf(mx, __shfl_xor(mx, 32));
    const float sub = mx + ns;

    unsigned pk_[16][2];
#pragma unroll
    for (int nf = 0; nf < 16; nf++) {
#pragma unroll
        for (int p = 0; p < 2; p++) {
            float v0 = RATIO * (__expf(pr[nf][2 * p]     - sub) + 1e-6f);
            float v1 = RATIO * (__expf(pr[nf][2 * p + 1] - sub) + 1e-6f);
            f16x2 pq = {(_Float16)v0, (_Float16)v1};
            pk_[nf][p] = __builtin_bit_cast(unsigned, pq);
        }
    }
    __syncthreads();   // kvs staged (drains vmcnt; hidden under phase 1)

    f32x4 acc[5];
#pragma unroll
    for (int n2 = 0; n2 < 5; n2++) acc[n2] = (f32x4){0.f, 0.f, 0.f, 0.f};
#pragma unroll
    for (int ks = 0; ks < 8; ks++) {
        unsigned u0 = __shfl(pk_[2 * ks][0], srcA);
        unsigned u1 = __shfl(pk_[2 * ks][1], srcA);
        unsigned u2 = __shfl(pk_[2 * ks][0], srcB);
        unsigned u3 = __shfl(pk_[2 * ks][1], srcB);
        unsigned v0 = __shfl(pk_[2 * ks + 1][0], srcA);
        unsigned v1 = __shfl(pk_[2 * ks + 1][1], srcA);
        unsigned v2 = __shfl(pk_[2 * ks + 1][0], srcB);
        unsigned v3 = __shfl(pk_[2 * ks + 1][1], srcB);
        u32x4 wv;
        wv[0] = hi ? v0 : u0;
        wv[1] = hi ? v1 : u1;
        wv[2] = hi ? v2 : u2;
        wv[3] = hi ? v3 : u3;
        f16x8 af = __builtin_bit_cast(f16x8, wv);
#pragma unroll
        for (int n2 = 0; n2 < 5; n2++) {
            f16x8 bfv = *(const f16x8*)&kvs[((n2 * 8 + ks) * 64 + lane) * 8];
            acc[n2] = __builtin_amdgcn_mfma_f32_16x16x32_f16(af, bfv, acc[n2], 0, 0, 0);
        }
    }
#pragma unroll
    for (int r = 0; r < 4; r++) {
        float den = __shfl(acc[4][r], (lane & 48));
        float inv = 1.f / fmaxf(den, 1e-6f);
        const int row = l0 + w * 16 + kq * 4 + r;
        _Float16* dst = ao + (size_t)(b * L + row) * D + h * DK;
#pragma unroll
        for (int n2 = 0; n2 < 4; n2++)
            dst[n2 * 16 + fr] = (_Float16)(acc[n2][r] * inv);
    }
}

extern "C" void kernel_launch(void* const* d_in, const int* in_sizes, int n_in,
                              void* d_out, int out_size, void* d_ws, size_t ws_size,
                              hipStream_t stream) {
    (void)in_sizes; (void)n_in; (void)out_size; (void)ws_size;
    const float* X    = (const float*)d_in[0];
    const int*   mask = (const int*)d_in[1];
    const float* Wq   = (const float*)d_in[2];
    const float* Wk   = (const float*)d_in[3];
    const float* Wv   = (const float*)d_in[4];
    const float* Wo   = (const float*)d_in[5];
    const float* P    = (const float*)d_in[6];

    char* ws = (char*)d_ws;
    _Float16* Xh    = (_Float16*)ws;                      // 0..32M
    _Float16* kvb   = (_Float16*)(ws + 33554432);         // 32M..96M  [k|v] stride 2048
    _Float16* attn  = (_Float16*)(ws + 33554432);         // reuses dead kvb space after kv_kernel
    _Float16* bufQ  = (_Float16*)(ws + 67108864);         // reuses dead kvb space after kv_kernel
    float* kvpart   = (float*)(ws + 100663296);           // 32MB
    float* kspart   = (float*)(ws + 134217728);           // 512KB
    _Float16* kvt   = (_Float16*)(ws + 134742016);        // 2.62MB
    _Float16* Wall  = (_Float16*)(ws + 137363456);        // 8MB [Wk;Wv;Wq;Wo]
    _Float16* Phf   = (_Float16*)(ws + 145752064);        // 32KB
    float* out      = (float*)d_out;

    dim3 blk(256);
    hipLaunchKernelGGL(cast_f32_f16, dim3(8192), blk, 0, stream, X, Xh, 2097152);
    hipLaunchKernelGGL(cast_w4, dim3(512, 4), blk, 0, stream, Wk, Wv, Wq, Wo, Wall);
    hipLaunchKernelGGL(cast_P_frag, dim3(1), blk, 0, stream, P, Phf);

    // K+V fused projection: C[16384][2048] = Xh @ [Wk;Wv]^T  (256^2 tiles, 512 thr)
    hipLaunchKernelGGL((gemm256<_Float16>), dim3(8, 64), dim3(512), 0, stream, Xh, Wall, kvb, 2048, D);

    hipLaunchKernelGGL(kv_kernel4, dim3(NCH, B * H), blk, 0, stream, kvb, mask, Phf, kvpart, kspart);
    hipLaunchKernelGGL(reduce_kvt2, dim3(4, 64), blk, 0, stream, kvpart, kspart, kvt);

    // Q projection (into dead kvb space)
    hipLaunchKernelGGL((gemm256<_Float16>), dim3(4, 64), dim3(512), 0, stream, Xh, Wall + 2 * 1048576, bufQ, D, D);

    hipLaunchKernelGGL(out_kernel8, dim3(L / 64, B * H), blk, 0, stream, bufQ, Phf, kvt, attn);

    hipLaunchKernelGGL((gemm256<float>), dim3(4, 64), dim3(512), 0, stream, attn, Wall + 3 * 1048576, out, D, D);
}